// Round 8
// baseline (486.488 us; speedup 1.0000x reference)
//
#include <hip/hip_runtime.h>

typedef unsigned short u16;
typedef unsigned int   u32;
typedef _Float16 f16;
typedef __attribute__((ext_vector_type(8))) _Float16 f16x8;
typedef __attribute__((ext_vector_type(4))) float f32x4;

#define NN  400
#define EIN 3200
#define NE  3600
#define TT  2016
#define L2E 1.4426950408889634f

__device__ __forceinline__ u32 pk16(float a, float b){
  auto h = __builtin_amdgcn_cvt_pkrtz(a,b);
  union { decltype(h) v; u32 u; } cv; cv.v = h; return cv.u;
}
__device__ __forceinline__ float hlo(u32 w){
  union { u32 u; __fp16 h[2]; } v; v.u=w; return (float)v.h[0];
}
__device__ __forceinline__ float hhi(u32 w){
  union { u32 u; __fp16 h[2]; } v; v.u=w; return (float)v.h[1];
}
// f32 += f16(lo/hi of u32) * f32, single VALU op (f32 accumulate, exact same numerics as cvt+fma)
__device__ __forceinline__ void fmix_lo(float& a, u32 s, float p){
  asm("v_fma_mix_f32 %0, %1, %2, %0 op_sel:[0,0,0] op_sel_hi:[1,0,0]" : "+v"(a) : "v"(s), "v"(p));
}
__device__ __forceinline__ void fmix_hi(float& a, u32 s, float p){
  asm("v_fma_mix_f32 %0, %1, %2, %0 op_sel:[1,0,0] op_sel_hi:[1,0,0]" : "+v"(a) : "v"(s), "v"(p));
}

// =============== setup: block0 = CSR (parallel scatter+sort), block1 = folds + B-frag packs ===============
__global__ __launch_bounds__(1024) void k_setup(
    const int* __restrict__ ei,
    const float* __restrict__ Wp2, const float* __restrict__ bp2,
    const float* __restrict__ Wt1,
    const float* __restrict__ at1_src, const float* __restrict__ at1_dst,
    const float* __restrict__ Wt2, const float* __restrict__ at2_src, const float* __restrict__ at2_dst,
    const float* __restrict__ Wh1,
    const float* __restrict__ Wc2, const float* __restrict__ bc2,
    const float* __restrict__ Ws1, const float* __restrict__ Ws2,
    u16* __restrict__ rp, u32* __restrict__ col2, u16* __restrict__ ord,
    f16* __restrict__ Bf1, f16* __restrict__ Bf2, f16* __restrict__ Bfh,
    f16* __restrict__ Bs1, f16* __restrict__ Bs2,
    float* __restrict__ wpe_s, float* __restrict__ wpe_d,
    float* __restrict__ wt1_as, float* __restrict__ wt1_ad,
    float* __restrict__ w2s, float* __restrict__ w2d,
    float* __restrict__ b_pe2, float* __restrict__ WcW,
    float* __restrict__ wbal_s, float* __restrict__ wbal_d,
    float* __restrict__ balc_s, float* __restrict__ balc_d)
{
  const int tid=threadIdx.x;
  __shared__ int s_src[NE]; __shared__ int s_dst[NE]; __shared__ int s_tmp[NE];
  __shared__ int s_deg[NN]; __shared__ int s_rp[NN+1]; __shared__ int s_cur[NN];
  __shared__ float sWpe[8192];
  __shared__ float sWcW[8192];
  __shared__ float sbpe2[256];
  if(blockIdx.x==0){
    for(int e2=tid;e2<NE;e2+=1024){
      s_src[e2]=(e2<EIN)?ei[e2]:(e2-EIN);
      s_dst[e2]=(e2<EIN)?ei[EIN+e2]:(e2-EIN);
    }
    if(tid<NN) s_deg[tid]=0;
    __syncthreads();
    for(int e2=tid;e2<NE;e2+=1024) atomicAdd(&s_deg[s_dst[e2]],1);
    __syncthreads();
    if(tid<=NN){
      int acc=0;
      for(int j=0;j<tid;j++) acc+=s_deg[j];
      s_rp[tid]=acc;
      rp[tid]=(u16)acc;
      if(tid<NN) s_cur[tid]=acc;
    }
    if(tid==0){
      rp[NN+1]=(u16)NE; rp[NN+2]=(u16)NE; rp[NN+3]=(u16)NE;
      col2[NE]=0; col2[NE+1]=0; col2[NE+2]=0; col2[NE+3]=0;
    }
    __syncthreads();
    for(int e2=tid;e2<NE;e2+=1024){
      int slot=atomicAdd(&s_cur[s_dst[e2]],1);
      s_tmp[slot]=e2;
    }
    __syncthreads();
    if(tid<NN){
      int b=s_rp[tid], en=s_rp[tid+1];
      for(int i=b+1;i<en;i++){
        int key=s_tmp[i]; int j=i-1;
        while(j>=b && s_tmp[j]>key){ s_tmp[j+1]=s_tmp[j]; j--; }
        s_tmp[j+1]=key;
      }
      for(int i=b;i<en;i++){
        u32 s=(u32)s_src[s_tmp[i]];
        col2[i]=((s*144u)<<16)|(s*4u);
      }
      int dg=en-b, rk=0;
      for(int j=0;j<NN;j++){
        int dj=s_rp[j+1]-s_rp[j];
        rk += (dj>dg)||((dj==dg)&&(j<tid));
      }
      ord[rk]=(u16)tid;
    }
  } else {
    for(int i=tid;i<8192;i+=1024){
      int k=i>>8, j=i&255;
      float a=0.f,b=0.f;
      for(int m=0;m<32;m++){
        a+=Wp2[k*32+m]*Wt1[(64+m)*256+j];
        b+=Wc2[k*32+m]*Wt1[(32+m)*256+j];
      }
      sWpe[i]=a; sWcW[i]=b; WcW[i]=b;
    }
    if(tid<256){
      float a=0.f,b=0.f;
      for(int m=0;m<32;m++){ a+=bp2[m]*Wt1[(64+m)*256+tid]; b+=bc2[m]*Wt1[(32+m)*256+tid]; }
      sbpe2[tid]=a+b; b_pe2[tid]=a+b;
    }
    __syncthreads();
    if(tid<128){
      int k=tid>>2,h=tid&3;
      float s=0,d=0,s2=0,d2=0,bs=0,bd=0;
      for(int c=0;c<64;c++){
        float as=at1_src[h*64+c], ad=at1_dst[h*64+c];
        float wv=sWpe[k*256+h*64+c];  s+=wv*as;  d+=wv*ad;
        float w2=Wt1[k*256+h*64+c];   s2+=w2*as; d2+=w2*ad;
        float wc=sWcW[k*256+h*64+c];  bs+=wc*as; bd+=wc*ad;
      }
      wpe_s[tid]=s*L2E; wpe_d[tid]=d*L2E; wt1_as[tid]=s2*L2E; wt1_ad[tid]=d2*L2E;
      wbal_s[tid]=bs*L2E; wbal_d[tid]=bd*L2E;
    }
    if(tid>=128&&tid<192){
      int k=tid-128; float s=0,d=0;
      for(int c=0;c<64;c++){ float wv=Wt2[k*64+c]; s+=wv*at2_src[c]; d+=wv*at2_dst[c]; }
      w2s[k]=s*L2E; w2d[k]=d*L2E;
    }
    if(tid>=192&&tid<196){
      int h=tid-192; float s=0,d=0;
      for(int c=0;c<64;c++){ float v=sbpe2[h*64+c]; s+=v*at1_src[h*64+c]; d+=v*at1_dst[h*64+c]; }
      balc_s[h]=s*L2E; balc_d[h]=d*L2E;
    }
    for(int i=tid;i<16384;i+=1024){
      int j=i&7, ll=(i>>3)&63, ks=(i>>9)&1, nt=(i>>10)&3, h=(i>>12)&3;
      int k=ks*32+(ll>>4)*8+j, c=h*64+nt*16+(ll&15);
      float v=(k<32)? sWpe[k*256+c] : Wt1[(k-32)*256+c];
      Bf1[i]=(f16)v;
    }
    for(int i=tid;i<4096;i+=1024){
      int j=i&7, ll=(i>>3)&63, ks=(i>>9)&1, nt=(i>>10)&3;
      Bf2[i]=(f16)Wt2[(ks*32+(ll>>4)*8+j)*64 + nt*16+(ll&15)];
    }
    for(int i=tid;i<2048;i+=1024){
      int j=i&7, ll=(i>>3)&63, ks=(i>>9)&1, nt=(i>>10)&1;
      Bfh[i]=(f16)Wh1[(ks*32+(ll>>4)*8+j)*32 + nt*16+(ll&15)];
    }
    for(int i=tid;i<4096;i+=1024){
      int j=i&7, ll=(i>>3)&63, nt=(i>>9)&7;
      int k=(ll>>4)*8+j, c=nt*16+(ll&15);
      Bs1[i]=(f16)((k<16)? Ws1[k*128+c] : 0.f);
    }
    for(int i=tid;i<1024;i+=1024){
      int j=i&7, ll=(i>>3)&63, nt=(i>>9)&1;
      int k=(ll>>4)*8+j, c=nt*16+(ll&15);
      Bs2[i]=(f16)Ws2[k*32+c];
    }
  }
}

// =============== static 2-layer GAT (unchanged from round 7) ===============
#define KS_X    0
#define KS_H    32000
#define KS_ALS  140800
#define KS_ALD  147200
#define KS_COL  153600
#define KS_RP   160800
#define KS_ORD  161608
#define KS_AS   162408
#define KS_AD   162920
#define KS_END  163432

__global__ __launch_bounds__(1024) void k_static(
    const float* __restrict__ x_static,
    const float* __restrict__ as1_src, const float* __restrict__ as1_dst, const float* __restrict__ bs1,
    const float* __restrict__ as2_src, const float* __restrict__ as2_dst, const float* __restrict__ bs2,
    const float* __restrict__ wt1_as, const float* __restrict__ wt1_ad,
    const f16* __restrict__ Bs1, const f16* __restrict__ Bs2,
    const u16* __restrict__ g_rp, const u32* __restrict__ g_col2, const u16* __restrict__ g_ord,
    u32* __restrict__ xsb, float* __restrict__ Aal_s, float* __restrict__ Aal_d)
{
  __shared__ __align__(16) char smem[KS_END];
  const int tid=threadIdx.x;
  const int l=tid&63, w=tid>>6;
  const int col16=l&15, cr=(l>>4)*4, kbyte=(l>>4)*16;
  const int lane8=tid&7, grp8=tid>>3;
  const int l16=tid&15, g16=tid>>4, hh=l16>>2, cg=l16&3;
  float* ALS=(float*)(smem+KS_ALS);
  float* ALD=(float*)(smem+KS_ALD);
  const u16* COL=(const u16*)(smem+KS_COL);
  const u16* RP =(const u16*)(smem+KS_RP);
  const u16* ORD=(const u16*)(smem+KS_ORD);
  float* AS=(float*)(smem+KS_AS);
  float* AD=(float*)(smem+KS_AD);

  for(int i=tid;i<NN*32;i+=1024){
    int n=i>>5, c=i&31;
    *(f16*)(smem+KS_X+n*80+c*2) = (c<16)? (f16)x_static[n*16+c] : (f16)0.f;
  }
  for(int i=tid;i<NE;i+=1024) ((u16*)(smem+KS_COL))[i]=(u16)((g_col2[i]&0xffffu)>>2);
  if(tid<202) ((u32*)(smem+KS_RP))[tid]=((const u32*)g_rp)[tid];
  else if(tid>=256&&tid<456) ((u32*)(smem+KS_ORD))[tid-256]=((const u32*)g_ord)[tid-256];
  else if(tid>=512&&tid<640){ AS[tid-512]=as1_src[tid-512]*L2E; AD[tid-512]=as1_dst[tid-512]*L2E; }
  __syncthreads();

  {
    f16x8 B[8];
    #pragma unroll
    for(int nt=0;nt<8;nt++) B[nt]=*(const f16x8*)(Bs1+nt*512+l*8);
    for(int mt=w;mt<25;mt+=16){
      f16x8 a=*(const f16x8*)(smem+KS_X+(mt*16+col16)*80+kbyte);
      #pragma unroll
      for(int nt=0;nt<8;nt++){
        f32x4 c={0.f,0.f,0.f,0.f};
        c=__builtin_amdgcn_mfma_f32_16x16x32_f16(a,B[nt],c,0,0,0);
        #pragma unroll
        for(int r=0;r<4;r++)
          *(f16*)(smem+KS_H+(mt*16+cr+r)*272+(nt*16+col16)*2)=(f16)c[r];
      }
    }
  }
  __syncthreads();

  if(tid<NN){
    #pragma unroll
    for(int h=0;h<4;h++){
      const u32* hr=(const u32*)(smem+KS_H+tid*272+h*64);
      float sa=0.f,da=0.f;
      #pragma unroll
      for(int q=0;q<16;q++){
        u32 v=hr[q]; float v0=hlo(v),v1=hhi(v);
        sa=fmaf(v0,AS[h*32+2*q],sa); sa=fmaf(v1,AS[h*32+2*q+1],sa);
        da=fmaf(v0,AD[h*32+2*q],da); da=fmaf(v1,AD[h*32+2*q+1],da);
      }
      ALS[tid*4+h]=sa; ALD[tid*4+h]=da;
    }
  }
  __syncthreads();

  for(int m=0;m<7;m++){
    int di=g16+m*64;
    if(di<NN){
      int d=ORD[di];
      int b=RP[d], en=RP[d+1];
      float ad=ALD[d*4+hh];
      float den=0.f;
      float rt[8]={0.f,0.f,0.f,0.f,0.f,0.f,0.f,0.f};
      for(int j=b;j<en;j++){
        int s=COL[j];
        float v=ALS[s*4+hh]+ad;
        v=fmaxf(v,0.2f*v);
        float p=__builtin_amdgcn_exp2f(v); den+=p;
        uint4 hw=*(const uint4*)(smem+KS_H+s*272+l16*16);
        rt[0]=fmaf(hlo(hw.x),p,rt[0]); rt[1]=fmaf(hhi(hw.x),p,rt[1]);
        rt[2]=fmaf(hlo(hw.y),p,rt[2]); rt[3]=fmaf(hhi(hw.y),p,rt[3]);
        rt[4]=fmaf(hlo(hw.z),p,rt[4]); rt[5]=fmaf(hhi(hw.z),p,rt[5]);
        rt[6]=fmaf(hlo(hw.w),p,rt[6]); rt[7]=fmaf(hhi(hw.w),p,rt[7]);
      }
      float inv=__builtin_amdgcn_rcpf(den);
      float vs[8];
      #pragma unroll
      for(int q=0;q<8;q++){
        float x=rt[q]*inv;
        x+=__shfl_xor(x,4); x+=__shfl_xor(x,8);
        vs[q]=x;
      }
      if(l16<4){
        u32 pk[4];
        #pragma unroll
        for(int q=0;q<4;q++){
          float v0=fmaxf(fmaf(0.25f,vs[2*q],  bs1[cg*8+2*q]),  0.f);
          float v1=fmaxf(fmaf(0.25f,vs[2*q+1],bs1[cg*8+2*q+1]),0.f);
          pk[q]=pk16(v0,v1);
        }
        *(uint4*)(smem+KS_X+d*80+cg*16)=make_uint4(pk[0],pk[1],pk[2],pk[3]);
      }
    }
  }
  __syncthreads();

  {
    f16x8 B[2];
    #pragma unroll
    for(int nt=0;nt<2;nt++) B[nt]=*(const f16x8*)(Bs2+nt*512+l*8);
    for(int mt=w;mt<25;mt+=16){
      f16x8 a=*(const f16x8*)(smem+KS_X+(mt*16+col16)*80+kbyte);
      #pragma unroll
      for(int nt=0;nt<2;nt++){
        f32x4 c={0.f,0.f,0.f,0.f};
        c=__builtin_amdgcn_mfma_f32_16x16x32_f16(a,B[nt],c,0,0,0);
        #pragma unroll
        for(int r=0;r<4;r++)
          *(f16*)(smem+KS_H+(mt*16+cr+r)*80+(nt*16+col16)*2)=(f16)c[r];
      }
    }
  }
  if(tid>=512&&tid<640){ AS[tid-512]=wt1_as[tid-512]; AD[tid-512]=wt1_ad[tid-512]; }
  __syncthreads();

  if(tid<NN){
    const u32* hr=(const u32*)(smem+KS_H+tid*80);
    float sa=0.f,da=0.f;
    #pragma unroll
    for(int q=0;q<16;q++){
      u32 v=hr[q]; float v0=hlo(v),v1=hhi(v);
      sa=fmaf(v0,as2_src[2*q],sa); sa=fmaf(v1,as2_src[2*q+1],sa);
      da=fmaf(v0,as2_dst[2*q],da); da=fmaf(v1,as2_dst[2*q+1],da);
    }
    ALS[tid]=sa*L2E; ALD[tid]=da*L2E;
  }
  __syncthreads();

  #pragma unroll
  for(int m=0;m<4;m++){
    int di=grp8+m*128;
    if(di<NN){
      int d=ORD[di];
      int b=RP[d], en=RP[d+1];
      float ad=ALD[d];
      float den=0.f;
      float rt[4]={0.f,0.f,0.f,0.f};
      for(int j=b;j<en;j++){
        int s=COL[j];
        float v=ALS[s]+ad;
        v=fmaxf(v,0.2f*v);
        float p=__builtin_amdgcn_exp2f(v); den+=p;
        uint2 hw=*(const uint2*)(smem+KS_H+s*80+lane8*8);
        rt[0]=fmaf(hlo(hw.x),p,rt[0]); rt[1]=fmaf(hhi(hw.x),p,rt[1]);
        rt[2]=fmaf(hlo(hw.y),p,rt[2]); rt[3]=fmaf(hhi(hw.y),p,rt[3]);
      }
      float inv=__builtin_amdgcn_rcpf(den);
      float xq[4];
      #pragma unroll
      for(int q=0;q<4;q++) xq[q]=fmaxf(fmaf(rt[q],inv,bs2[lane8*4+q]),0.f);
      float ps[4]={0.f,0.f,0.f,0.f}, pd[4]={0.f,0.f,0.f,0.f};
      #pragma unroll
      for(int q=0;q<4;q++){
        int k=lane8*4+q;
        #pragma unroll
        for(int h2=0;h2<4;h2++){ ps[h2]=fmaf(xq[q],AS[k*4+h2],ps[h2]); pd[h2]=fmaf(xq[q],AD[k*4+h2],pd[h2]); }
      }
      #pragma unroll
      for(int h2=0;h2<4;h2++){
        ps[h2]+=__shfl_xor(ps[h2],1); ps[h2]+=__shfl_xor(ps[h2],2); ps[h2]+=__shfl_xor(ps[h2],4);
        pd[h2]+=__shfl_xor(pd[h2],1); pd[h2]+=__shfl_xor(pd[h2],2); pd[h2]+=__shfl_xor(pd[h2],4);
      }
      if(lane8==0){
        #pragma unroll
        for(int h2=0;h2<4;h2++){ Aal_s[d*4+h2]=ps[h2]; Aal_d[d*4+h2]=pd[h2]; }
      }
      xsb[d*16+lane8*2+0]=pk16(xq[0],xq[1]);
      xsb[d*16+lane8*2+1]=pk16(xq[2],xq[3]);
    }
  }
}

// =============== fused temporal: fma_mix gather + swapped-operand MFMA + deferred-store overlap ===============
#define OT_A    0
#define OT_H    57600
#define OT_ALS  115200
#define OT_ALD  121600
#define OT_COL  128000
#define OT_RP   142416
#define OT_ORD  143232
#define OT_BP   144032
#define OT_WPES 145056
#define OT_WPED 145568
#define OT_W2S  146080
#define OT_W2D  146336
#define OT_BT2  146592
#define OT_BH1  146848
#define OT_WH2  146976
#define OT_BPMT 147104
#define OT_C1   147360
#define OT_FEAT 147488
#define OT_BAL  147616
#define OT_END  147648

__global__ __launch_bounds__(1024) void k_temporal(
    const float* __restrict__ pf, const float* __restrict__ Wp1, const float* __restrict__ bp1,
    const u32* __restrict__ xsb, const float* __restrict__ Aal_s, const float* __restrict__ Aal_d,
    const float* __restrict__ wpe_sg, const float* __restrict__ wpe_dg,
    const f16* __restrict__ Bf1, const f16* __restrict__ Bf2, const f16* __restrict__ Bfh,
    const float* __restrict__ WcW, const float* __restrict__ b_pe2,
    const float* __restrict__ wbal_s, const float* __restrict__ wbal_d,
    const float* __restrict__ balc_s, const float* __restrict__ balc_d,
    const float* __restrict__ Wc1, const float* __restrict__ bc1,
    const float* __restrict__ wd_emb, const float* __restrict__ sl_emb,
    const float* __restrict__ bt1, const float* __restrict__ w2sg, const float* __restrict__ w2dg,
    const float* __restrict__ bt2g, const float* __restrict__ bh1g,
    const float* __restrict__ Wh2g, const float* __restrict__ bh2,
    const u16* __restrict__ g_rp, const u32* __restrict__ g_col2, const u16* __restrict__ g_ord,
    float* __restrict__ Hout, float* __restrict__ pred)
{
  __shared__ __align__(16) char smem[OT_END];
  const int bid=blockIdx.x;
  const int t=(bid&7)*252+(bid>>3);   // XCD-chunked bijective swizzle
  const int tid=threadIdx.x;
  const int l=tid&63, w=tid>>6;
  const int lane4=tid&3, grp4=tid>>2;
  const int col16=l&15, cr=(l>>4)*4, kbyte=(l>>4)*16;

  float4 pA=make_float4(0,0,0,0), pB=make_float4(0,0,0,0);
  if(tid<NN){ const float4* pp=(const float4*)(pf+((size_t)tid*TT+(size_t)t)*8); pA=pp[0]; pB=pp[1]; }

  // ---- phase 0: staging ----
  for(int i=tid;i<3604;i+=1024) ((u32*)(smem+OT_COL))[i]=g_col2[i];
  for(int i=tid;i<6400;i+=1024){ int n=i>>4,q=i&15; *(u32*)(smem+OT_A+n*144+64+q*4)=xsb[i]; }
  if(tid<202) ((u32*)(smem+OT_RP))[tid]=((const u32*)g_rp)[tid];
  else if(tid>=256&&tid<456) ((u32*)(smem+OT_ORD))[tid-256]=((const u32*)g_ord)[tid-256];
  else if(tid>=512&&tid<640){ ((float*)(smem+OT_WPES))[tid-512]=wpe_sg[tid-512]; ((float*)(smem+OT_WPED))[tid-512]=wpe_dg[tid-512]; }
  else if(tid>=640&&tid<704){ ((float*)(smem+OT_W2S))[tid-640]=w2sg[tid-640]; ((float*)(smem+OT_W2D))[tid-640]=w2dg[tid-640]; }
  else if(tid>=704&&tid<768){ ((float*)(smem+OT_BT2))[tid-704]=bt2g[tid-704]; }
  else if(tid>=768&&tid<800){ ((float*)(smem+OT_BH1))[tid-768]=bh1g[tid-768]; ((float*)(smem+OT_WH2))[tid-768]=Wh2g[tid-768]; }
  else if(tid>=832&&tid<864){
    int q=tid-832;
    const int wd=t/288, sl=t%288;
    float v=0.f;
    if(q<8) v=wd_emb[wd*8+q];
    else if(q<24) v=sl_emb[sl*16+(q-8)];
    else if(q==24||q==25){ float ta=0.021816615649929116f*(float)sl; v=(q==24)?__sinf(ta):__cosf(ta); }
    else if(q==26||q==27){ float wa=0.8975979010256552f*(float)wd; v=(q==26)?__sinf(wa):__cosf(wa); }
    else if(q==28) v=(wd>=5)?1.f:0.f;
    ((float*)(smem+OT_FEAT))[q]=v;
  }
  __syncthreads();

  // ---- phase 1: c1 (calendar) || P1 + logits ----
  if(tid>=512&&tid<544){
    int q=tid-512;
    float a=bc1[q];
    const float* F=(const float*)(smem+OT_FEAT);
    for(int k=0;k<29;k++) a+=F[k]*Wc1[k*32+q];
    ((float*)(smem+OT_C1))[q]=fmaxf(a,0.f);
  }
  if(tid<NN){
    float px[8]={pA.x,pA.y,pA.z,pA.w,pB.x,pB.y,pB.z,pB.w};
    float pv[32];
    #pragma unroll
    for(int k2=0;k2<32;k2+=2){
      float a0=bp1[k2], a1=bp1[k2+1];
      #pragma unroll
      for(int i2=0;i2<8;i2++){ a0=fmaf(px[i2],Wp1[i2*32+k2],a0); a1=fmaf(px[i2],Wp1[i2*32+k2+1],a1); }
      a0=fmaxf(a0,0.f); a1=fmaxf(a1,0.f);
      pv[k2]=a0; pv[k2+1]=a1;
      *(u32*)(smem+OT_A+tid*144+k2*2)=pk16(a0,a1);
    }
    const float* WS=(const float*)(smem+OT_WPES);
    const float* WD=(const float*)(smem+OT_WPED);
    #pragma unroll
    for(int h=0;h<4;h++){
      float sa=Aal_s[tid*4+h], da=Aal_d[tid*4+h];
      #pragma unroll
      for(int k2=0;k2<32;k2++){ sa=fmaf(pv[k2],WS[k2*4+h],sa); da=fmaf(pv[k2],WD[k2*4+h],da); }
      ((float*)(smem+OT_ALS))[tid*4+h]=sa;
      ((float*)(smem+OT_ALD))[tid*4+h]=da;
    }
  }
  __syncthreads();

  // MFMA with weights as A-operand (D row = feature, D col = node) -> packed b64 stores.
  f32x4 c0[4], c1[4];
  auto mfma_compute=[&](int h){
    f16x8 Bw0[4],Bw1[4];
    #pragma unroll
    for(int nt=0;nt<4;nt++){
      Bw0[nt]=*(const f16x8*)(Bf1+(((h*4+nt)*2+0)*512+l*8));
      Bw1[nt]=*(const f16x8*)(Bf1+(((h*4+nt)*2+1)*512+l*8));
    }
    {
      const char* arow=smem+OT_A+(w*16+col16)*144;
      f16x8 a0=*(const f16x8*)(arow+kbyte);
      f16x8 a1=*(const f16x8*)(arow+64+kbyte);
      #pragma unroll
      for(int nt=0;nt<4;nt++){
        f32x4 c={0.f,0.f,0.f,0.f};
        c=__builtin_amdgcn_mfma_f32_16x16x32_f16(Bw0[nt],a0,c,0,0,0);
        c=__builtin_amdgcn_mfma_f32_16x16x32_f16(Bw1[nt],a1,c,0,0,0);
        c0[nt]=c;
      }
    }
    if(w<9){
      const char* arow=smem+OT_A+((w+16)*16+col16)*144;
      f16x8 a0=*(const f16x8*)(arow+kbyte);
      f16x8 a1=*(const f16x8*)(arow+64+kbyte);
      #pragma unroll
      for(int nt=0;nt<4;nt++){
        f32x4 c={0.f,0.f,0.f,0.f};
        c=__builtin_amdgcn_mfma_f32_16x16x32_f16(Bw0[nt],a0,c,0,0,0);
        c=__builtin_amdgcn_mfma_f32_16x16x32_f16(Bw1[nt],a1,c,0,0,0);
        c1[nt]=c;
      }
    }
  };
  auto mfma_store=[&](){
    int n0=w*16+col16;
    #pragma unroll
    for(int nt=0;nt<4;nt++)
      *(uint2*)(smem+OT_H+n0*144+(nt*16+cr)*2)=make_uint2(pk16(c0[nt][0],c0[nt][1]),pk16(c0[nt][2],c0[nt][3]));
    if(w<9){
      int n1=(w+16)*16+col16;
      #pragma unroll
      for(int nt=0;nt<4;nt++)
        *(uint2*)(smem+OT_H+n1*144+(nt*16+cr)*2)=make_uint2(pk16(c1[nt][0],c1[nt][1]),pk16(c1[nt][2],c1[nt][3]));
    }
  };

  // ---- phase 2: MFMA head0 (compute+store) || bpre || Bal ----
  mfma_compute(0);
  mfma_store();
  if(tid<256){
    float a=b_pe2[tid];
    const float* C1=(const float*)(smem+OT_C1);
    for(int k2=0;k2<32;k2++) a=fmaf(C1[k2],WcW[k2*256+tid],a);
    ((float*)(smem+OT_BP))[tid]=a;
  }
  if(tid>=256&&tid<264){
    int h=tid&3; bool isd=(tid>=260);
    const float* C1=(const float*)(smem+OT_C1);
    const float* wb=isd?wbal_d:wbal_s;
    float a=isd?balc_d[h]:balc_s[h];
    for(int k2=0;k2<32;k2++) a=fmaf(C1[k2],wb[k2*4+h],a);
    ((float*)(smem+OT_BAL))[(isd?4:0)+h]=a;
  }
  __syncthreads();

  const u16* RP  =(const u16*)(smem+OT_RP);
  const u16* ORD =(const u16*)(smem+OT_ORD);
  const u32* COL2=(const u32*)(smem+OT_COL);
  const char* HB = smem+OT_H+lane4*32;

  float acc[2][16];
  #pragma unroll
  for(int m=0;m<2;m++){
    #pragma unroll
    for(int q=0;q<16;q++) acc[m][q]=0.f;
  }

  // ---- L1: 4 heads; gather(h) overlapped with MFMA-compute(h+1) (regs), store deferred past barrier ----
  for(int h=0;h<4;h++){
    if(h==0&&tid<64){
      const float* BP=(const float*)(smem+OT_BP);
      ((float*)(smem+OT_BPMT))[tid]=0.25f*(BP[tid]+BP[64+tid]+BP[128+tid]+BP[192+tid])+bt1[tid];
    }
    if(h<3) mfma_compute(h+1);
    const float* ALD=(const float*)(smem+OT_ALD);
    const char* ALSb=smem+OT_ALS+h*4;
    float bsd=((const float*)(smem+OT_BAL))[h]+((const float*)(smem+OT_BAL))[4+h];
    #pragma unroll
    for(int m=0;m<2;m++){
      int di = m ? (511-grp4) : grp4;
      float rt[16];
      #pragma unroll
      for(int q=0;q<16;q++) rt[q]=0.f;
      float inv=0.f;
      if(di<NN){
        int d=ORD[di];
        int b=RP[d], en=RP[d+1];
        float ad=ALD[d*4+h]+bsd;
        float den=0.f;
        for(int j=b;j<en;j++){
          u32 cv=COL2[j];
          float alv=*(const float*)(ALSb+((cv&0xffffu)<<2));
          float v=alv+ad;
          v=fmaxf(v,0.2f*v);
          float p=__builtin_amdgcn_exp2f(v); den+=p;
          const char* hp=HB+(cv>>16);
          uint4 h0=*(const uint4*)(hp);
          uint4 h1=*(const uint4*)(hp+16);
          fmix_lo(rt[0],h0.x,p);  fmix_hi(rt[1],h0.x,p);
          fmix_lo(rt[2],h0.y,p);  fmix_hi(rt[3],h0.y,p);
          fmix_lo(rt[4],h0.z,p);  fmix_hi(rt[5],h0.z,p);
          fmix_lo(rt[6],h0.w,p);  fmix_hi(rt[7],h0.w,p);
          fmix_lo(rt[8],h1.x,p);  fmix_hi(rt[9],h1.x,p);
          fmix_lo(rt[10],h1.y,p); fmix_hi(rt[11],h1.y,p);
          fmix_lo(rt[12],h1.z,p); fmix_hi(rt[13],h1.z,p);
          fmix_lo(rt[14],h1.w,p); fmix_hi(rt[15],h1.w,p);
        }
        inv=__builtin_amdgcn_rcpf(den);
      }
      #pragma unroll
      for(int q=0;q<16;q++) acc[m][q]=fmaf(rt[q],inv,acc[m][q]);
    }
    __syncthreads();
    if(h<3){ mfma_store(); __syncthreads(); }
  }

  // ---- g1 = relu(0.25*acc + bpmt) + logits2 + pack ----
  {
    const float* BPMT=(const float*)(smem+OT_BPMT);
    const float* W2S=(const float*)(smem+OT_W2S);
    const float* W2D=(const float*)(smem+OT_W2D);
    #pragma unroll
    for(int m=0;m<2;m++){
      int di = m ? (511-grp4) : grp4;
      if(di<NN){
        int d=ORD[di];
        float g[16];
        #pragma unroll
        for(int q=0;q<16;q++) g[q]=fmaxf(fmaf(0.25f,acc[m][q],BPMT[lane4*16+q]),0.f);
        float ss=0.f,dd2=0.f;
        #pragma unroll
        for(int q=0;q<16;q++){ ss=fmaf(g[q],W2S[lane4*16+q],ss); dd2=fmaf(g[q],W2D[lane4*16+q],dd2); }
        ss+=__shfl_xor(ss,1); ss+=__shfl_xor(ss,2);
        dd2+=__shfl_xor(dd2,1); dd2+=__shfl_xor(dd2,2);
        if(lane4==0){ ((float*)(smem+OT_ALS))[d]=ss; ((float*)(smem+OT_ALD))[d]=dd2; }
        uint4 pk0,pk1;
        pk0.x=pk16(g[0],g[1]);   pk0.y=pk16(g[2],g[3]);   pk0.z=pk16(g[4],g[5]);   pk0.w=pk16(g[6],g[7]);
        pk1.x=pk16(g[8],g[9]);   pk1.y=pk16(g[10],g[11]); pk1.z=pk16(g[12],g[13]); pk1.w=pk16(g[14],g[15]);
        *(uint4*)(smem+OT_A+d*144+lane4*32)=pk0;
        *(uint4*)(smem+OT_A+d*144+lane4*32+16)=pk1;
      }
    }
  }
  __syncthreads();

  // ---- L2 MFMA (swapped operands, packed stores) ----
  {
    f16x8 Bw0[4],Bw1[4];
    #pragma unroll
    for(int nt=0;nt<4;nt++){
      Bw0[nt]=*(const f16x8*)(Bf2+((nt*2+0)*512+l*8));
      Bw1[nt]=*(const f16x8*)(Bf2+((nt*2+1)*512+l*8));
    }
    for(int mt=w;mt<25;mt+=16){
      const char* arow=smem+OT_A+(mt*16+col16)*144;
      f16x8 a0=*(const f16x8*)(arow+kbyte);
      f16x8 a1=*(const f16x8*)(arow+64+kbyte);
      int n=mt*16+col16;
      #pragma unroll
      for(int nt=0;nt<4;nt++){
        f32x4 c={0.f,0.f,0.f,0.f};
        c=__builtin_amdgcn_mfma_f32_16x16x32_f16(Bw0[nt],a0,c,0,0,0);
        c=__builtin_amdgcn_mfma_f32_16x16x32_f16(Bw1[nt],a1,c,0,0,0);
        *(uint2*)(smem+OT_H+n*144+(nt*16+cr)*2)=make_uint2(pk16(c[0],c[1]),pk16(c[2],c[3]));
      }
    }
  }
  __syncthreads();

  // ---- L2 agg (fma_mix) -> Hout + pack for MLP ----
  {
    const float* ALD=(const float*)(smem+OT_ALD);
    const float* BT2=(const float*)(smem+OT_BT2);
    #pragma unroll
    for(int m=0;m<2;m++){
      int di = m ? (511-grp4) : grp4;
      if(di<NN){
        int d=ORD[di];
        int b=RP[d], en=RP[d+1];
        float ad=ALD[d];
        float den=0.f;
        float rt[16];
        #pragma unroll
        for(int q=0;q<16;q++) rt[q]=0.f;
        for(int j=b;j<en;j++){
          u32 cv=COL2[j];
          float alv=*(const float*)(smem+OT_ALS+(cv&0xffffu));
          float v=alv+ad;
          v=fmaxf(v,0.2f*v);
          float p=__builtin_amdgcn_exp2f(v); den+=p;
          const char* hp=HB+(cv>>16);
          uint4 h0=*(const uint4*)(hp);
          uint4 h1=*(const uint4*)(hp+16);
          fmix_lo(rt[0],h0.x,p);  fmix_hi(rt[1],h0.x,p);
          fmix_lo(rt[2],h0.y,p);  fmix_hi(rt[3],h0.y,p);
          fmix_lo(rt[4],h0.z,p);  fmix_hi(rt[5],h0.z,p);
          fmix_lo(rt[6],h0.w,p);  fmix_hi(rt[7],h0.w,p);
          fmix_lo(rt[8],h1.x,p);  fmix_hi(rt[9],h1.x,p);
          fmix_lo(rt[10],h1.y,p); fmix_hi(rt[11],h1.y,p);
          fmix_lo(rt[12],h1.z,p); fmix_hi(rt[13],h1.z,p);
          fmix_lo(rt[14],h1.w,p); fmix_hi(rt[15],h1.w,p);
        }
        float inv=__builtin_amdgcn_rcpf(den);
        float hv[16];
        #pragma unroll
        for(int q=0;q<16;q++) hv[q]=fmaxf(fmaf(rt[q],inv,BT2[lane4*16+q]),0.f);
        float* hp2=Hout+((size_t)t*NN+d)*64+lane4*16;
        *(float4*)(hp2)   =make_float4(hv[0],hv[1],hv[2],hv[3]);
        *(float4*)(hp2+4) =make_float4(hv[4],hv[5],hv[6],hv[7]);
        *(float4*)(hp2+8) =make_float4(hv[8],hv[9],hv[10],hv[11]);
        *(float4*)(hp2+12)=make_float4(hv[12],hv[13],hv[14],hv[15]);
        uint4 pk0,pk1;
        pk0.x=pk16(hv[0],hv[1]);   pk0.y=pk16(hv[2],hv[3]);   pk0.z=pk16(hv[4],hv[5]);   pk0.w=pk16(hv[6],hv[7]);
        pk1.x=pk16(hv[8],hv[9]);   pk1.y=pk16(hv[10],hv[11]); pk1.z=pk16(hv[12],hv[13]); pk1.w=pk16(hv[14],hv[15]);
        *(uint4*)(smem+OT_A+d*144+lane4*32)=pk0;
        *(uint4*)(smem+OT_A+d*144+lane4*32+16)=pk1;
      }
    }
  }
  __syncthreads();

  // ---- head MLP (swapped operands, f32x4 stores): pj = relu(H@Wh1+bh1) ----
  {
    f16x8 Bw0[2],Bw1[2];
    #pragma unroll
    for(int nt=0;nt<2;nt++){
      Bw0[nt]=*(const f16x8*)(Bfh+((nt*2+0)*512+l*8));
      Bw1[nt]=*(const f16x8*)(Bfh+((nt*2+1)*512+l*8));
    }
    for(int mt=w;mt<25;mt+=16){
      const char* arow=smem+OT_A+(mt*16+col16)*144;
      f16x8 a0=*(const f16x8*)(arow+kbyte);
      f16x8 a1=*(const f16x8*)(arow+64+kbyte);
      int n=mt*16+col16;
      #pragma unroll
      for(int nt=0;nt<2;nt++){
        float4 bj=*(const float4*)(smem+OT_BH1+(nt*16+cr)*4);
        f32x4 c={bj.x,bj.y,bj.z,bj.w};
        c=__builtin_amdgcn_mfma_f32_16x16x32_f16(Bw0[nt],a0,c,0,0,0);
        c=__builtin_amdgcn_mfma_f32_16x16x32_f16(Bw1[nt],a1,c,0,0,0);
        f32x4 co={fmaxf(c[0],0.f),fmaxf(c[1],0.f),fmaxf(c[2],0.f),fmaxf(c[3],0.f)};
        *(f32x4*)(smem+OT_H+n*144+(nt*16+cr)*4)=co;
      }
    }
  }
  __syncthreads();

  // ---- pred ----
  {
    const float* WH2=(const float*)(smem+OT_WH2);
    float wv[8];
    #pragma unroll
    for(int q=0;q<8;q++) wv[q]=WH2[lane4*8+q];
    float bb=bh2[0];
    #pragma unroll
    for(int m=0;m<2;m++){
      int di = m ? (511-grp4) : grp4;
      if(di<NN){
        int d=ORD[di];
        float4 p0=*(const float4*)(smem+OT_H+d*144+lane4*32);
        float4 p1=*(const float4*)(smem+OT_H+d*144+lane4*32+16);
        float sp=p0.x*wv[0]+p0.y*wv[1]+p0.z*wv[2]+p0.w*wv[3]
                +p1.x*wv[4]+p1.y*wv[5]+p1.z*wv[6]+p1.w*wv[7];
        sp+=__shfl_xor(sp,1); sp+=__shfl_xor(sp,2);
        if(lane4==0) pred[(size_t)t*NN+d]=sp+bb;
      }
    }
  }
}

extern "C" void kernel_launch(void* const* d_in, const int* in_sizes, int n_in,
                              void* d_out, int out_size, void* d_ws, size_t ws_size,
                              hipStream_t stream) {
  const float* x_static=(const float*)d_in[0];
  const float* pf      =(const float*)d_in[1];
  const int*   ei      =(const int*)  d_in[2];
  const float* Ws1=(const float*)d_in[3];
  const float* as1_src=(const float*)d_in[4];
  const float* as1_dst=(const float*)d_in[5];
  const float* bs1=(const float*)d_in[6];
  const float* Ws2=(const float*)d_in[7];
  const float* as2_src=(const float*)d_in[8];
  const float* as2_dst=(const float*)d_in[9];
  const float* bs2=(const float*)d_in[10];
  const float* wd_emb=(const float*)d_in[11];
  const float* sl_emb=(const float*)d_in[12];
  const float* Wc1=(const float*)d_in[13];
  const float* bc1=(const float*)d_in[14];
  const float* Wc2=(const float*)d_in[15];
  const float* bc2=(const float*)d_in[16];
  const float* Wp1=(const float*)d_in[17];
  const float* bp1=(const float*)d_in[18];
  const float* Wp2=(const float*)d_in[19];
  const float* bp2=(const float*)d_in[20];
  const float* Wt1=(const float*)d_in[21];
  const float* at1_src=(const float*)d_in[22];
  const float* at1_dst=(const float*)d_in[23];
  const float* bt1=(const float*)d_in[24];
  const float* Wt2=(const float*)d_in[25];
  const float* at2_src=(const float*)d_in[26];
  const float* at2_dst=(const float*)d_in[27];
  const float* bt2=(const float*)d_in[28];
  const float* Wh1=(const float*)d_in[29];
  const float* bh1=(const float*)d_in[30];
  const float* Wh2=(const float*)d_in[31];
  const float* bh2=(const float*)d_in[32];

  float* Hout=(float*)d_out;
  float* pred=Hout + (size_t)TT*NN*64;

  char* wsp=(char*)d_ws; size_t off=0;
  auto A=[&](size_t n)->void*{ void* p=wsp+off; off=(off+n+255)&~(size_t)255; return p; };
  u16* rp    =(u16*)A(408*2);
  u32* col2  =(u32*)A((NE+4)*4);
  u16* ordv  =(u16*)A(NN*2);
  f16* Bf1   =(f16*)A(16384*2);
  f16* Bf2   =(f16*)A(4096*2);
  f16* Bfh   =(f16*)A(2048*2);
  f16* Bs1   =(f16*)A(4096*2);
  f16* Bs2   =(f16*)A(1024*2);
  float* wpe_s =(float*)A(128*4);
  float* wpe_d =(float*)A(128*4);
  float* wt1_as=(float*)A(128*4);
  float* wt1_ad=(float*)A(128*4);
  float* w2s   =(float*)A(64*4);
  float* w2d   =(float*)A(64*4);
  float* b_pe2 =(float*)A(256*4);
  float* WcW   =(float*)A(8192*4);
  float* wbal_s=(float*)A(128*4);
  float* wbal_d=(float*)A(128*4);
  float* balc_s=(float*)A(4*4);
  float* balc_d=(float*)A(4*4);
  u32*   xsb   =(u32*)A(6400*4);
  float* Aal_s =(float*)A(1600*4);
  float* Aal_d =(float*)A(1600*4);

  hipLaunchKernelGGL(k_setup, dim3(2), dim3(1024), 0, stream,
                     ei, Wp2,bp2,Wt1,at1_src,at1_dst,Wt2,at2_src,at2_dst,Wh1,Wc2,bc2,Ws1,Ws2,
                     rp,col2,ordv,Bf1,Bf2,Bfh,Bs1,Bs2,
                     wpe_s,wpe_d,wt1_as,wt1_ad,w2s,w2d,b_pe2,WcW,wbal_s,wbal_d,balc_s,balc_d);
  hipLaunchKernelGGL(k_static, dim3(1), dim3(1024), 0, stream,
                     x_static,as1_src,as1_dst,bs1,as2_src,as2_dst,bs2,
                     wt1_as,wt1_ad,Bs1,Bs2,rp,col2,ordv,xsb,Aal_s,Aal_d);
  hipLaunchKernelGGL(k_temporal, dim3(TT), dim3(1024), 0, stream,
                     pf,Wp1,bp1,xsb,Aal_s,Aal_d,wpe_s,wpe_d,Bf1,Bf2,Bfh,
                     WcW,b_pe2,wbal_s,wbal_d,balc_s,balc_d,
                     Wc1,bc1,wd_emb,sl_emb,bt1,w2s,w2d,bt2,bh1,Wh2,bh2,
                     rp,col2,ordv,Hout,pred);
}

// Round 9
// 405.217 us; speedup vs baseline: 1.2006x; 1.2006x over previous
//
#include <hip/hip_runtime.h>

typedef unsigned short u16;
typedef unsigned int   u32;
typedef _Float16 f16;
typedef __attribute__((ext_vector_type(8))) _Float16 f16x8;
typedef __attribute__((ext_vector_type(4))) float f32x4;

#define NN  400
#define EIN 3200
#define NE  3600
#define TT  2016
#define L2E 1.4426950408889634f

__device__ __forceinline__ u32 pk16(float a, float b){
  auto h = __builtin_amdgcn_cvt_pkrtz(a,b);
  union { decltype(h) v; u32 u; } cv; cv.v = h; return cv.u;
}
__device__ __forceinline__ float hlo(u32 w){
  union { u32 u; __fp16 h[2]; } v; v.u=w; return (float)v.h[0];
}
__device__ __forceinline__ float hhi(u32 w){
  union { u32 u; __fp16 h[2]; } v; v.u=w; return (float)v.h[1];
}
// f32 += f16(lo/hi of u32) * f32, single VALU op
__device__ __forceinline__ void fmix_lo(float& a, u32 s, float p){
  asm("v_fma_mix_f32 %0, %1, %2, %0 op_sel:[0,0,0] op_sel_hi:[1,0,0]" : "+v"(a) : "v"(s), "v"(p));
}
__device__ __forceinline__ void fmix_hi(float& a, u32 s, float p){
  asm("v_fma_mix_f32 %0, %1, %2, %0 op_sel:[1,0,0] op_sel_hi:[1,0,0]" : "+v"(a) : "v"(s), "v"(p));
}

// =============== setup: block0 = CSR (parallel scatter+sort), block1 = folds + B-frag packs ===============
__global__ __launch_bounds__(1024) void k_setup(
    const int* __restrict__ ei,
    const float* __restrict__ Wp2, const float* __restrict__ bp2,
    const float* __restrict__ Wt1,
    const float* __restrict__ at1_src, const float* __restrict__ at1_dst,
    const float* __restrict__ Wt2, const float* __restrict__ at2_src, const float* __restrict__ at2_dst,
    const float* __restrict__ Wh1,
    const float* __restrict__ Wc2, const float* __restrict__ bc2,
    const float* __restrict__ Ws1, const float* __restrict__ Ws2,
    u16* __restrict__ rp, u32* __restrict__ col2, u16* __restrict__ ord,
    f16* __restrict__ Bf1, f16* __restrict__ Bf2, f16* __restrict__ Bfh,
    f16* __restrict__ Bs1, f16* __restrict__ Bs2,
    float* __restrict__ wpe_s, float* __restrict__ wpe_d,
    float* __restrict__ wt1_as, float* __restrict__ wt1_ad,
    float* __restrict__ w2s, float* __restrict__ w2d,
    float* __restrict__ b_pe2, float* __restrict__ WcW,
    float* __restrict__ wbal_s, float* __restrict__ wbal_d,
    float* __restrict__ balc_s, float* __restrict__ balc_d)
{
  const int tid=threadIdx.x;
  __shared__ int s_src[NE]; __shared__ int s_dst[NE]; __shared__ int s_tmp[NE];
  __shared__ int s_deg[NN]; __shared__ int s_rp[NN+1]; __shared__ int s_cur[NN];
  __shared__ float sWpe[8192];
  __shared__ float sWcW[8192];
  __shared__ float sbpe2[256];
  if(blockIdx.x==0){
    for(int e2=tid;e2<NE;e2+=1024){
      s_src[e2]=(e2<EIN)?ei[e2]:(e2-EIN);
      s_dst[e2]=(e2<EIN)?ei[EIN+e2]:(e2-EIN);
    }
    if(tid<NN) s_deg[tid]=0;
    __syncthreads();
    for(int e2=tid;e2<NE;e2+=1024) atomicAdd(&s_deg[s_dst[e2]],1);
    __syncthreads();
    if(tid<=NN){
      int acc=0;
      for(int j=0;j<tid;j++) acc+=s_deg[j];
      s_rp[tid]=acc;
      rp[tid]=(u16)acc;
      if(tid<NN) s_cur[tid]=acc;
    }
    if(tid==0){
      rp[NN+1]=(u16)NE; rp[NN+2]=(u16)NE; rp[NN+3]=(u16)NE;
      col2[NE]=0; col2[NE+1]=0; col2[NE+2]=0; col2[NE+3]=0;
    }
    __syncthreads();
    for(int e2=tid;e2<NE;e2+=1024){
      int slot=atomicAdd(&s_cur[s_dst[e2]],1);
      s_tmp[slot]=e2;
    }
    __syncthreads();
    if(tid<NN){
      int b=s_rp[tid], en=s_rp[tid+1];
      for(int i=b+1;i<en;i++){
        int key=s_tmp[i]; int j=i-1;
        while(j>=b && s_tmp[j]>key){ s_tmp[j+1]=s_tmp[j]; j--; }
        s_tmp[j+1]=key;
      }
      for(int i=b;i<en;i++){
        u32 s=(u32)s_src[s_tmp[i]];
        col2[i]=((s*144u)<<16)|(s*4u);
      }
      int dg=en-b, rk=0;
      for(int j=0;j<NN;j++){
        int dj=s_rp[j+1]-s_rp[j];
        rk += (dj>dg)||((dj==dg)&&(j<tid));
      }
      ord[rk]=(u16)tid;
    }
  } else {
    for(int i=tid;i<8192;i+=1024){
      int k=i>>8, j=i&255;
      float a=0.f,b=0.f;
      for(int m=0;m<32;m++){
        a+=Wp2[k*32+m]*Wt1[(64+m)*256+j];
        b+=Wc2[k*32+m]*Wt1[(32+m)*256+j];
      }
      sWpe[i]=a; sWcW[i]=b; WcW[i]=b;
    }
    if(tid<256){
      float a=0.f,b=0.f;
      for(int m=0;m<32;m++){ a+=bp2[m]*Wt1[(64+m)*256+tid]; b+=bc2[m]*Wt1[(32+m)*256+tid]; }
      sbpe2[tid]=a+b; b_pe2[tid]=a+b;
    }
    __syncthreads();
    if(tid<128){
      int k=tid>>2,h=tid&3;
      float s=0,d=0,s2=0,d2=0,bs=0,bd=0;
      for(int c=0;c<64;c++){
        float as=at1_src[h*64+c], ad=at1_dst[h*64+c];
        float wv=sWpe[k*256+h*64+c];  s+=wv*as;  d+=wv*ad;
        float w2=Wt1[k*256+h*64+c];   s2+=w2*as; d2+=w2*ad;
        float wc=sWcW[k*256+h*64+c];  bs+=wc*as; bd+=wc*ad;
      }
      wpe_s[tid]=s*L2E; wpe_d[tid]=d*L2E; wt1_as[tid]=s2*L2E; wt1_ad[tid]=d2*L2E;
      wbal_s[tid]=bs*L2E; wbal_d[tid]=bd*L2E;
    }
    if(tid>=128&&tid<192){
      int k=tid-128; float s=0,d=0;
      for(int c=0;c<64;c++){ float wv=Wt2[k*64+c]; s+=wv*at2_src[c]; d+=wv*at2_dst[c]; }
      w2s[k]=s*L2E; w2d[k]=d*L2E;
    }
    if(tid>=192&&tid<196){
      int h=tid-192; float s=0,d=0;
      for(int c=0;c<64;c++){ float v=sbpe2[h*64+c]; s+=v*at1_src[h*64+c]; d+=v*at1_dst[h*64+c]; }
      balc_s[h]=s*L2E; balc_d[h]=d*L2E;
    }
    for(int i=tid;i<16384;i+=1024){
      int j=i&7, ll=(i>>3)&63, ks=(i>>9)&1, nt=(i>>10)&3, h=(i>>12)&3;
      int k=ks*32+(ll>>4)*8+j, c=h*64+nt*16+(ll&15);
      float v=(k<32)? sWpe[k*256+c] : Wt1[(k-32)*256+c];
      Bf1[i]=(f16)v;
    }
    for(int i=tid;i<4096;i+=1024){
      int j=i&7, ll=(i>>3)&63, ks=(i>>9)&1, nt=(i>>10)&3;
      Bf2[i]=(f16)Wt2[(ks*32+(ll>>4)*8+j)*64 + nt*16+(ll&15)];
    }
    for(int i=tid;i<2048;i+=1024){
      int j=i&7, ll=(i>>3)&63, ks=(i>>9)&1, nt=(i>>10)&1;
      Bfh[i]=(f16)Wh1[(ks*32+(ll>>4)*8+j)*32 + nt*16+(ll&15)];
    }
    for(int i=tid;i<4096;i+=1024){
      int j=i&7, ll=(i>>3)&63, nt=(i>>9)&7;
      int k=(ll>>4)*8+j, c=nt*16+(ll&15);
      Bs1[i]=(f16)((k<16)? Ws1[k*128+c] : 0.f);
    }
    for(int i=tid;i<1024;i+=1024){
      int j=i&7, ll=(i>>3)&63, nt=(i>>9)&1;
      int k=(ll>>4)*8+j, c=nt*16+(ll&15);
      Bs2[i]=(f16)Ws2[k*32+c];
    }
  }
}

// =============== static 2-layer GAT (unchanged) ===============
#define KS_X    0
#define KS_H    32000
#define KS_ALS  140800
#define KS_ALD  147200
#define KS_COL  153600
#define KS_RP   160800
#define KS_ORD  161608
#define KS_AS   162408
#define KS_AD   162920
#define KS_END  163432

__global__ __launch_bounds__(1024) void k_static(
    const float* __restrict__ x_static,
    const float* __restrict__ as1_src, const float* __restrict__ as1_dst, const float* __restrict__ bs1,
    const float* __restrict__ as2_src, const float* __restrict__ as2_dst, const float* __restrict__ bs2,
    const float* __restrict__ wt1_as, const float* __restrict__ wt1_ad,
    const f16* __restrict__ Bs1, const f16* __restrict__ Bs2,
    const u16* __restrict__ g_rp, const u32* __restrict__ g_col2, const u16* __restrict__ g_ord,
    u32* __restrict__ xsb, float* __restrict__ Aal_s, float* __restrict__ Aal_d)
{
  __shared__ __align__(16) char smem[KS_END];
  const int tid=threadIdx.x;
  const int l=tid&63, w=tid>>6;
  const int col16=l&15, cr=(l>>4)*4, kbyte=(l>>4)*16;
  const int lane8=tid&7, grp8=tid>>3;
  const int l16=tid&15, g16=tid>>4, hh=l16>>2, cg=l16&3;
  float* ALS=(float*)(smem+KS_ALS);
  float* ALD=(float*)(smem+KS_ALD);
  const u16* COL=(const u16*)(smem+KS_COL);
  const u16* RP =(const u16*)(smem+KS_RP);
  const u16* ORD=(const u16*)(smem+KS_ORD);
  float* AS=(float*)(smem+KS_AS);
  float* AD=(float*)(smem+KS_AD);

  for(int i=tid;i<NN*32;i+=1024){
    int n=i>>5, c=i&31;
    *(f16*)(smem+KS_X+n*80+c*2) = (c<16)? (f16)x_static[n*16+c] : (f16)0.f;
  }
  for(int i=tid;i<NE;i+=1024) ((u16*)(smem+KS_COL))[i]=(u16)((g_col2[i]&0xffffu)>>2);
  if(tid<202) ((u32*)(smem+KS_RP))[tid]=((const u32*)g_rp)[tid];
  else if(tid>=256&&tid<456) ((u32*)(smem+KS_ORD))[tid-256]=((const u32*)g_ord)[tid-256];
  else if(tid>=512&&tid<640){ AS[tid-512]=as1_src[tid-512]*L2E; AD[tid-512]=as1_dst[tid-512]*L2E; }
  __syncthreads();

  {
    f16x8 B[8];
    #pragma unroll
    for(int nt=0;nt<8;nt++) B[nt]=*(const f16x8*)(Bs1+nt*512+l*8);
    for(int mt=w;mt<25;mt+=16){
      f16x8 a=*(const f16x8*)(smem+KS_X+(mt*16+col16)*80+kbyte);
      #pragma unroll
      for(int nt=0;nt<8;nt++){
        f32x4 c={0.f,0.f,0.f,0.f};
        c=__builtin_amdgcn_mfma_f32_16x16x32_f16(a,B[nt],c,0,0,0);
        #pragma unroll
        for(int r=0;r<4;r++)
          *(f16*)(smem+KS_H+(mt*16+cr+r)*272+(nt*16+col16)*2)=(f16)c[r];
      }
    }
  }
  __syncthreads();

  if(tid<NN){
    #pragma unroll
    for(int h=0;h<4;h++){
      const u32* hr=(const u32*)(smem+KS_H+tid*272+h*64);
      float sa=0.f,da=0.f;
      #pragma unroll
      for(int q=0;q<16;q++){
        u32 v=hr[q]; float v0=hlo(v),v1=hhi(v);
        sa=fmaf(v0,AS[h*32+2*q],sa); sa=fmaf(v1,AS[h*32+2*q+1],sa);
        da=fmaf(v0,AD[h*32+2*q],da); da=fmaf(v1,AD[h*32+2*q+1],da);
      }
      ALS[tid*4+h]=sa; ALD[tid*4+h]=da;
    }
  }
  __syncthreads();

  for(int m=0;m<7;m++){
    int di=g16+m*64;
    if(di<NN){
      int d=ORD[di];
      int b=RP[d], en=RP[d+1];
      float ad=ALD[d*4+hh];
      float den=0.f;
      float rt[8]={0.f,0.f,0.f,0.f,0.f,0.f,0.f,0.f};
      for(int j=b;j<en;j++){
        int s=COL[j];
        float v=ALS[s*4+hh]+ad;
        v=fmaxf(v,0.2f*v);
        float p=__builtin_amdgcn_exp2f(v); den+=p;
        uint4 hw=*(const uint4*)(smem+KS_H+s*272+l16*16);
        rt[0]=fmaf(hlo(hw.x),p,rt[0]); rt[1]=fmaf(hhi(hw.x),p,rt[1]);
        rt[2]=fmaf(hlo(hw.y),p,rt[2]); rt[3]=fmaf(hhi(hw.y),p,rt[3]);
        rt[4]=fmaf(hlo(hw.z),p,rt[4]); rt[5]=fmaf(hhi(hw.z),p,rt[5]);
        rt[6]=fmaf(hlo(hw.w),p,rt[6]); rt[7]=fmaf(hhi(hw.w),p,rt[7]);
      }
      float inv=__builtin_amdgcn_rcpf(den);
      float vs[8];
      #pragma unroll
      for(int q=0;q<8;q++){
        float x=rt[q]*inv;
        x+=__shfl_xor(x,4); x+=__shfl_xor(x,8);
        vs[q]=x;
      }
      if(l16<4){
        u32 pk[4];
        #pragma unroll
        for(int q=0;q<4;q++){
          float v0=fmaxf(fmaf(0.25f,vs[2*q],  bs1[cg*8+2*q]),  0.f);
          float v1=fmaxf(fmaf(0.25f,vs[2*q+1],bs1[cg*8+2*q+1]),0.f);
          pk[q]=pk16(v0,v1);
        }
        *(uint4*)(smem+KS_X+d*80+cg*16)=make_uint4(pk[0],pk[1],pk[2],pk[3]);
      }
    }
  }
  __syncthreads();

  {
    f16x8 B[2];
    #pragma unroll
    for(int nt=0;nt<2;nt++) B[nt]=*(const f16x8*)(Bs2+nt*512+l*8);
    for(int mt=w;mt<25;mt+=16){
      f16x8 a=*(const f16x8*)(smem+KS_X+(mt*16+col16)*80+kbyte);
      #pragma unroll
      for(int nt=0;nt<2;nt++){
        f32x4 c={0.f,0.f,0.f,0.f};
        c=__builtin_amdgcn_mfma_f32_16x16x32_f16(a,B[nt],c,0,0,0);
        #pragma unroll
        for(int r=0;r<4;r++)
          *(f16*)(smem+KS_H+(mt*16+cr+r)*80+(nt*16+col16)*2)=(f16)c[r];
      }
    }
  }
  if(tid>=512&&tid<640){ AS[tid-512]=wt1_as[tid-512]; AD[tid-512]=wt1_ad[tid-512]; }
  __syncthreads();

  if(tid<NN){
    const u32* hr=(const u32*)(smem+KS_H+tid*80);
    float sa=0.f,da=0.f;
    #pragma unroll
    for(int q=0;q<16;q++){
      u32 v=hr[q]; float v0=hlo(v),v1=hhi(v);
      sa=fmaf(v0,as2_src[2*q],sa); sa=fmaf(v1,as2_src[2*q+1],sa);
      da=fmaf(v0,as2_dst[2*q],da); da=fmaf(v1,as2_dst[2*q+1],da);
    }
    ALS[tid]=sa*L2E; ALD[tid]=da*L2E;
  }
  __syncthreads();

  #pragma unroll
  for(int m=0;m<4;m++){
    int di=grp8+m*128;
    if(di<NN){
      int d=ORD[di];
      int b=RP[d], en=RP[d+1];
      float ad=ALD[d];
      float den=0.f;
      float rt[4]={0.f,0.f,0.f,0.f};
      for(int j=b;j<en;j++){
        int s=COL[j];
        float v=ALS[s]+ad;
        v=fmaxf(v,0.2f*v);
        float p=__builtin_amdgcn_exp2f(v); den+=p;
        uint2 hw=*(const uint2*)(smem+KS_H+s*80+lane8*8);
        rt[0]=fmaf(hlo(hw.x),p,rt[0]); rt[1]=fmaf(hhi(hw.x),p,rt[1]);
        rt[2]=fmaf(hlo(hw.y),p,rt[2]); rt[3]=fmaf(hhi(hw.y),p,rt[3]);
      }
      float inv=__builtin_amdgcn_rcpf(den);
      float xq[4];
      #pragma unroll
      for(int q=0;q<4;q++) xq[q]=fmaxf(fmaf(rt[q],inv,bs2[lane8*4+q]),0.f);
      float ps[4]={0.f,0.f,0.f,0.f}, pd[4]={0.f,0.f,0.f,0.f};
      #pragma unroll
      for(int q=0;q<4;q++){
        int k=lane8*4+q;
        #pragma unroll
        for(int h2=0;h2<4;h2++){ ps[h2]=fmaf(xq[q],AS[k*4+h2],ps[h2]); pd[h2]=fmaf(xq[q],AD[k*4+h2],pd[h2]); }
      }
      #pragma unroll
      for(int h2=0;h2<4;h2++){
        ps[h2]+=__shfl_xor(ps[h2],1); ps[h2]+=__shfl_xor(ps[h2],2); ps[h2]+=__shfl_xor(ps[h2],4);
        pd[h2]+=__shfl_xor(pd[h2],1); pd[h2]+=__shfl_xor(pd[h2],2); pd[h2]+=__shfl_xor(pd[h2],4);
      }
      if(lane8==0){
        #pragma unroll
        for(int h2=0;h2<4;h2++){ Aal_s[d*4+h2]=ps[h2]; Aal_d[d*4+h2]=pd[h2]; }
      }
      xsb[d*16+lane8*2+0]=pk16(xq[0],xq[1]);
      xsb[d*16+lane8*2+1]=pk16(xq[2],xq[3]);
    }
  }
}

// =============== fused temporal: fma_mix gather + swapped-operand MFMA (immediate store) ===============
#define OT_A    0
#define OT_H    57600
#define OT_ALS  115200
#define OT_ALD  121600
#define OT_COL  128000
#define OT_RP   142416
#define OT_ORD  143232
#define OT_BP   144032
#define OT_WPES 145056
#define OT_WPED 145568
#define OT_W2S  146080
#define OT_W2D  146336
#define OT_BT2  146592
#define OT_BH1  146848
#define OT_WH2  146976
#define OT_BPMT 147104
#define OT_C1   147360
#define OT_FEAT 147488
#define OT_BAL  147616
#define OT_END  147648

__global__ __launch_bounds__(1024) void k_temporal(
    const float* __restrict__ pf, const float* __restrict__ Wp1, const float* __restrict__ bp1,
    const u32* __restrict__ xsb, const float* __restrict__ Aal_s, const float* __restrict__ Aal_d,
    const float* __restrict__ wpe_sg, const float* __restrict__ wpe_dg,
    const f16* __restrict__ Bf1, const f16* __restrict__ Bf2, const f16* __restrict__ Bfh,
    const float* __restrict__ WcW, const float* __restrict__ b_pe2,
    const float* __restrict__ wbal_s, const float* __restrict__ wbal_d,
    const float* __restrict__ balc_s, const float* __restrict__ balc_d,
    const float* __restrict__ Wc1, const float* __restrict__ bc1,
    const float* __restrict__ wd_emb, const float* __restrict__ sl_emb,
    const float* __restrict__ bt1, const float* __restrict__ w2sg, const float* __restrict__ w2dg,
    const float* __restrict__ bt2g, const float* __restrict__ bh1g,
    const float* __restrict__ Wh2g, const float* __restrict__ bh2,
    const u16* __restrict__ g_rp, const u32* __restrict__ g_col2, const u16* __restrict__ g_ord,
    float* __restrict__ Hout, float* __restrict__ pred)
{
  __shared__ __align__(16) char smem[OT_END];
  const int bid=blockIdx.x;
  const int t=(bid&7)*252+(bid>>3);   // XCD-chunked bijective swizzle
  const int tid=threadIdx.x;
  const int l=tid&63, w=tid>>6;
  const int lane4=tid&3, grp4=tid>>2;
  const int col16=l&15, cr=(l>>4)*4, kbyte=(l>>4)*16;

  float4 pA=make_float4(0,0,0,0), pB=make_float4(0,0,0,0);
  if(tid<NN){ const float4* pp=(const float4*)(pf+((size_t)tid*TT+(size_t)t)*8); pA=pp[0]; pB=pp[1]; }

  // ---- phase 0: staging ----
  for(int i=tid;i<3604;i+=1024) ((u32*)(smem+OT_COL))[i]=g_col2[i];
  for(int i=tid;i<6400;i+=1024){ int n=i>>4,q=i&15; *(u32*)(smem+OT_A+n*144+64+q*4)=xsb[i]; }
  if(tid<202) ((u32*)(smem+OT_RP))[tid]=((const u32*)g_rp)[tid];
  else if(tid>=256&&tid<456) ((u32*)(smem+OT_ORD))[tid-256]=((const u32*)g_ord)[tid-256];
  else if(tid>=512&&tid<640){ ((float*)(smem+OT_WPES))[tid-512]=wpe_sg[tid-512]; ((float*)(smem+OT_WPED))[tid-512]=wpe_dg[tid-512]; }
  else if(tid>=640&&tid<704){ ((float*)(smem+OT_W2S))[tid-640]=w2sg[tid-640]; ((float*)(smem+OT_W2D))[tid-640]=w2dg[tid-640]; }
  else if(tid>=704&&tid<768){ ((float*)(smem+OT_BT2))[tid-704]=bt2g[tid-704]; }
  else if(tid>=768&&tid<800){ ((float*)(smem+OT_BH1))[tid-768]=bh1g[tid-768]; ((float*)(smem+OT_WH2))[tid-768]=Wh2g[tid-768]; }
  else if(tid>=832&&tid<864){
    int q=tid-832;
    const int wd=t/288, sl=t%288;
    float v=0.f;
    if(q<8) v=wd_emb[wd*8+q];
    else if(q<24) v=sl_emb[sl*16+(q-8)];
    else if(q==24||q==25){ float ta=0.021816615649929116f*(float)sl; v=(q==24)?__sinf(ta):__cosf(ta); }
    else if(q==26||q==27){ float wa=0.8975979010256552f*(float)wd; v=(q==26)?__sinf(wa):__cosf(wa); }
    else if(q==28) v=(wd>=5)?1.f:0.f;
    ((float*)(smem+OT_FEAT))[q]=v;
  }
  __syncthreads();

  // ---- phase 1: c1 (calendar) || P1 + logits ----
  if(tid>=512&&tid<544){
    int q=tid-512;
    float a=bc1[q];
    const float* F=(const float*)(smem+OT_FEAT);
    for(int k=0;k<29;k++) a+=F[k]*Wc1[k*32+q];
    ((float*)(smem+OT_C1))[q]=fmaxf(a,0.f);
  }
  if(tid<NN){
    float px[8]={pA.x,pA.y,pA.z,pA.w,pB.x,pB.y,pB.z,pB.w};
    float pv[32];
    #pragma unroll
    for(int k2=0;k2<32;k2+=2){
      float a0=bp1[k2], a1=bp1[k2+1];
      #pragma unroll
      for(int i2=0;i2<8;i2++){ a0=fmaf(px[i2],Wp1[i2*32+k2],a0); a1=fmaf(px[i2],Wp1[i2*32+k2+1],a1); }
      a0=fmaxf(a0,0.f); a1=fmaxf(a1,0.f);
      pv[k2]=a0; pv[k2+1]=a1;
      *(u32*)(smem+OT_A+tid*144+k2*2)=pk16(a0,a1);
    }
    const float* WS=(const float*)(smem+OT_WPES);
    const float* WD=(const float*)(smem+OT_WPED);
    #pragma unroll
    for(int h=0;h<4;h++){
      float sa=Aal_s[tid*4+h], da=Aal_d[tid*4+h];
      #pragma unroll
      for(int k2=0;k2<32;k2++){ sa=fmaf(pv[k2],WS[k2*4+h],sa); da=fmaf(pv[k2],WD[k2*4+h],da); }
      ((float*)(smem+OT_ALS))[tid*4+h]=sa;
      ((float*)(smem+OT_ALD))[tid*4+h]=da;
    }
  }
  __syncthreads();

  // MFMA with weights as A-operand (D row = feature, D col = node) -> packed b64 stores, immediate.
  auto mfma_L1=[&](int h){
    f16x8 Bw0[4],Bw1[4];
    #pragma unroll
    for(int nt=0;nt<4;nt++){
      Bw0[nt]=*(const f16x8*)(Bf1+(((h*4+nt)*2+0)*512+l*8));
      Bw1[nt]=*(const f16x8*)(Bf1+(((h*4+nt)*2+1)*512+l*8));
    }
    for(int mt=w;mt<25;mt+=16){
      const char* arow=smem+OT_A+(mt*16+col16)*144;
      f16x8 a0=*(const f16x8*)(arow+kbyte);
      f16x8 a1=*(const f16x8*)(arow+64+kbyte);
      int n=mt*16+col16;
      #pragma unroll
      for(int nt=0;nt<4;nt++){
        f32x4 c={0.f,0.f,0.f,0.f};
        c=__builtin_amdgcn_mfma_f32_16x16x32_f16(Bw0[nt],a0,c,0,0,0);
        c=__builtin_amdgcn_mfma_f32_16x16x32_f16(Bw1[nt],a1,c,0,0,0);
        *(uint2*)(smem+OT_H+n*144+(nt*16+cr)*2)=make_uint2(pk16(c[0],c[1]),pk16(c[2],c[3]));
      }
    }
  };

  // ---- phase 2: MFMA head0 || bpre || Bal ----
  mfma_L1(0);
  if(tid<256){
    float a=b_pe2[tid];
    const float* C1=(const float*)(smem+OT_C1);
    for(int k2=0;k2<32;k2++) a=fmaf(C1[k2],WcW[k2*256+tid],a);
    ((float*)(smem+OT_BP))[tid]=a;
  }
  if(tid>=256&&tid<264){
    int h=tid&3; bool isd=(tid>=260);
    const float* C1=(const float*)(smem+OT_C1);
    const float* wb=isd?wbal_d:wbal_s;
    float a=isd?balc_d[h]:balc_s[h];
    for(int k2=0;k2<32;k2++) a=fmaf(C1[k2],wb[k2*4+h],a);
    ((float*)(smem+OT_BAL))[(isd?4:0)+h]=a;
  }
  __syncthreads();

  const u16* RP  =(const u16*)(smem+OT_RP);
  const u16* ORD =(const u16*)(smem+OT_ORD);
  const u32* COL2=(const u32*)(smem+OT_COL);
  const char* HB = smem+OT_H+lane4*32;

  float acc[2][16];
  #pragma unroll
  for(int m=0;m<2;m++){
    #pragma unroll
    for(int q=0;q<16;q++) acc[m][q]=0.f;
  }

  // ---- L1: 4 heads, 4-lane-group fma_mix gather (snake order) ----
  for(int h=0;h<4;h++){
    if(h==0&&tid<64){
      const float* BP=(const float*)(smem+OT_BP);
      ((float*)(smem+OT_BPMT))[tid]=0.25f*(BP[tid]+BP[64+tid]+BP[128+tid]+BP[192+tid])+bt1[tid];
    }
    const float* ALD=(const float*)(smem+OT_ALD);
    const char* ALSb=smem+OT_ALS+h*4;
    float bsd=((const float*)(smem+OT_BAL))[h]+((const float*)(smem+OT_BAL))[4+h];
    #pragma unroll
    for(int m=0;m<2;m++){
      int di = m ? (511-grp4) : grp4;
      float rt[16];
      #pragma unroll
      for(int q=0;q<16;q++) rt[q]=0.f;
      float inv=0.f;
      if(di<NN){
        int d=ORD[di];
        int b=RP[d], en=RP[d+1];
        float ad=ALD[d*4+h]+bsd;
        float den=0.f;
        for(int j=b;j<en;j++){
          u32 cv=COL2[j];
          float alv=*(const float*)(ALSb+((cv&0xffffu)<<2));
          float v=alv+ad;
          v=fmaxf(v,0.2f*v);
          float p=__builtin_amdgcn_exp2f(v); den+=p;
          const char* hp=HB+(cv>>16);
          uint4 h0=*(const uint4*)(hp);
          uint4 h1=*(const uint4*)(hp+16);
          fmix_lo(rt[0],h0.x,p);  fmix_hi(rt[1],h0.x,p);
          fmix_lo(rt[2],h0.y,p);  fmix_hi(rt[3],h0.y,p);
          fmix_lo(rt[4],h0.z,p);  fmix_hi(rt[5],h0.z,p);
          fmix_lo(rt[6],h0.w,p);  fmix_hi(rt[7],h0.w,p);
          fmix_lo(rt[8],h1.x,p);  fmix_hi(rt[9],h1.x,p);
          fmix_lo(rt[10],h1.y,p); fmix_hi(rt[11],h1.y,p);
          fmix_lo(rt[12],h1.z,p); fmix_hi(rt[13],h1.z,p);
          fmix_lo(rt[14],h1.w,p); fmix_hi(rt[15],h1.w,p);
        }
        inv=__builtin_amdgcn_rcpf(den);
      }
      #pragma unroll
      for(int q=0;q<16;q++) acc[m][q]=fmaf(rt[q],inv,acc[m][q]);
    }
    __syncthreads();
    if(h<3){ mfma_L1(h+1); __syncthreads(); }
  }

  // ---- g1 = relu(0.25*acc + bpmt) + logits2 + pack ----
  {
    const float* BPMT=(const float*)(smem+OT_BPMT);
    const float* W2S=(const float*)(smem+OT_W2S);
    const float* W2D=(const float*)(smem+OT_W2D);
    #pragma unroll
    for(int m=0;m<2;m++){
      int di = m ? (511-grp4) : grp4;
      if(di<NN){
        int d=ORD[di];
        float g[16];
        #pragma unroll
        for(int q=0;q<16;q++) g[q]=fmaxf(fmaf(0.25f,acc[m][q],BPMT[lane4*16+q]),0.f);
        float ss=0.f,dd2=0.f;
        #pragma unroll
        for(int q=0;q<16;q++){ ss=fmaf(g[q],W2S[lane4*16+q],ss); dd2=fmaf(g[q],W2D[lane4*16+q],dd2); }
        ss+=__shfl_xor(ss,1); ss+=__shfl_xor(ss,2);
        dd2+=__shfl_xor(dd2,1); dd2+=__shfl_xor(dd2,2);
        if(lane4==0){ ((float*)(smem+OT_ALS))[d]=ss; ((float*)(smem+OT_ALD))[d]=dd2; }
        uint4 pk0,pk1;
        pk0.x=pk16(g[0],g[1]);   pk0.y=pk16(g[2],g[3]);   pk0.z=pk16(g[4],g[5]);   pk0.w=pk16(g[6],g[7]);
        pk1.x=pk16(g[8],g[9]);   pk1.y=pk16(g[10],g[11]); pk1.z=pk16(g[12],g[13]); pk1.w=pk16(g[14],g[15]);
        *(uint4*)(smem+OT_A+d*144+lane4*32)=pk0;
        *(uint4*)(smem+OT_A+d*144+lane4*32+16)=pk1;
      }
    }
  }
  __syncthreads();

  // ---- L2 MFMA (swapped operands, packed stores) ----
  {
    f16x8 Bw0[4],Bw1[4];
    #pragma unroll
    for(int nt=0;nt<4;nt++){
      Bw0[nt]=*(const f16x8*)(Bf2+((nt*2+0)*512+l*8));
      Bw1[nt]=*(const f16x8*)(Bf2+((nt*2+1)*512+l*8));
    }
    for(int mt=w;mt<25;mt+=16){
      const char* arow=smem+OT_A+(mt*16+col16)*144;
      f16x8 a0=*(const f16x8*)(arow+kbyte);
      f16x8 a1=*(const f16x8*)(arow+64+kbyte);
      int n=mt*16+col16;
      #pragma unroll
      for(int nt=0;nt<4;nt++){
        f32x4 c={0.f,0.f,0.f,0.f};
        c=__builtin_amdgcn_mfma_f32_16x16x32_f16(Bw0[nt],a0,c,0,0,0);
        c=__builtin_amdgcn_mfma_f32_16x16x32_f16(Bw1[nt],a1,c,0,0,0);
        *(uint2*)(smem+OT_H+n*144+(nt*16+cr)*2)=make_uint2(pk16(c[0],c[1]),pk16(c[2],c[3]));
      }
    }
  }
  __syncthreads();

  // ---- L2 agg (fma_mix) -> Hout + pack for MLP ----
  {
    const float* ALD=(const float*)(smem+OT_ALD);
    const float* BT2=(const float*)(smem+OT_BT2);
    #pragma unroll
    for(int m=0;m<2;m++){
      int di = m ? (511-grp4) : grp4;
      if(di<NN){
        int d=ORD[di];
        int b=RP[d], en=RP[d+1];
        float ad=ALD[d];
        float den=0.f;
        float rt[16];
        #pragma unroll
        for(int q=0;q<16;q++) rt[q]=0.f;
        for(int j=b;j<en;j++){
          u32 cv=COL2[j];
          float alv=*(const float*)(smem+OT_ALS+(cv&0xffffu));
          float v=alv+ad;
          v=fmaxf(v,0.2f*v);
          float p=__builtin_amdgcn_exp2f(v); den+=p;
          const char* hp=HB+(cv>>16);
          uint4 h0=*(const uint4*)(hp);
          uint4 h1=*(const uint4*)(hp+16);
          fmix_lo(rt[0],h0.x,p);  fmix_hi(rt[1],h0.x,p);
          fmix_lo(rt[2],h0.y,p);  fmix_hi(rt[3],h0.y,p);
          fmix_lo(rt[4],h0.z,p);  fmix_hi(rt[5],h0.z,p);
          fmix_lo(rt[6],h0.w,p);  fmix_hi(rt[7],h0.w,p);
          fmix_lo(rt[8],h1.x,p);  fmix_hi(rt[9],h1.x,p);
          fmix_lo(rt[10],h1.y,p); fmix_hi(rt[11],h1.y,p);
          fmix_lo(rt[12],h1.z,p); fmix_hi(rt[13],h1.z,p);
          fmix_lo(rt[14],h1.w,p); fmix_hi(rt[15],h1.w,p);
        }
        float inv=__builtin_amdgcn_rcpf(den);
        float hv[16];
        #pragma unroll
        for(int q=0;q<16;q++) hv[q]=fmaxf(fmaf(rt[q],inv,BT2[lane4*16+q]),0.f);
        float* hp2=Hout+((size_t)t*NN+d)*64+lane4*16;
        *(float4*)(hp2)   =make_float4(hv[0],hv[1],hv[2],hv[3]);
        *(float4*)(hp2+4) =make_float4(hv[4],hv[5],hv[6],hv[7]);
        *(float4*)(hp2+8) =make_float4(hv[8],hv[9],hv[10],hv[11]);
        *(float4*)(hp2+12)=make_float4(hv[12],hv[13],hv[14],hv[15]);
        uint4 pk0,pk1;
        pk0.x=pk16(hv[0],hv[1]);   pk0.y=pk16(hv[2],hv[3]);   pk0.z=pk16(hv[4],hv[5]);   pk0.w=pk16(hv[6],hv[7]);
        pk1.x=pk16(hv[8],hv[9]);   pk1.y=pk16(hv[10],hv[11]); pk1.z=pk16(hv[12],hv[13]); pk1.w=pk16(hv[14],hv[15]);
        *(uint4*)(smem+OT_A+d*144+lane4*32)=pk0;
        *(uint4*)(smem+OT_A+d*144+lane4*32+16)=pk1;
      }
    }
  }
  __syncthreads();

  // ---- head MLP (swapped operands, f32x4 stores): pj = relu(H@Wh1+bh1) ----
  {
    f16x8 Bw0[2],Bw1[2];
    #pragma unroll
    for(int nt=0;nt<2;nt++){
      Bw0[nt]=*(const f16x8*)(Bfh+((nt*2+0)*512+l*8));
      Bw1[nt]=*(const f16x8*)(Bfh+((nt*2+1)*512+l*8));
    }
    for(int mt=w;mt<25;mt+=16){
      const char* arow=smem+OT_A+(mt*16+col16)*144;
      f16x8 a0=*(const f16x8*)(arow+kbyte);
      f16x8 a1=*(const f16x8*)(arow+64+kbyte);
      int n=mt*16+col16;
      #pragma unroll
      for(int nt=0;nt<2;nt++){
        float4 bj=*(const float4*)(smem+OT_BH1+(nt*16+cr)*4);
        f32x4 c={bj.x,bj.y,bj.z,bj.w};
        c=__builtin_amdgcn_mfma_f32_16x16x32_f16(Bw0[nt],a0,c,0,0,0);
        c=__builtin_amdgcn_mfma_f32_16x16x32_f16(Bw1[nt],a1,c,0,0,0);
        f32x4 co={fmaxf(c[0],0.f),fmaxf(c[1],0.f),fmaxf(c[2],0.f),fmaxf(c[3],0.f)};
        *(f32x4*)(smem+OT_H+n*144+(nt*16+cr)*4)=co;
      }
    }
  }
  __syncthreads();

  // ---- pred ----
  {
    const float* WH2=(const float*)(smem+OT_WH2);
    float wv[8];
    #pragma unroll
    for(int q=0;q<8;q++) wv[q]=WH2[lane4*8+q];
    float bb=bh2[0];
    #pragma unroll
    for(int m=0;m<2;m++){
      int di = m ? (511-grp4) : grp4;
      if(di<NN){
        int d=ORD[di];
        float4 p0=*(const float4*)(smem+OT_H+d*144+lane4*32);
        float4 p1=*(const float4*)(smem+OT_H+d*144+lane4*32+16);
        float sp=p0.x*wv[0]+p0.y*wv[1]+p0.z*wv[2]+p0.w*wv[3]
                +p1.x*wv[4]+p1.y*wv[5]+p1.z*wv[6]+p1.w*wv[7];
        sp+=__shfl_xor(sp,1); sp+=__shfl_xor(sp,2);
        if(lane4==0) pred[(size_t)t*NN+d]=sp+bb;
      }
    }
  }
}

extern "C" void kernel_launch(void* const* d_in, const int* in_sizes, int n_in,
                              void* d_out, int out_size, void* d_ws, size_t ws_size,
                              hipStream_t stream) {
  const float* x_static=(const float*)d_in[0];
  const float* pf      =(const float*)d_in[1];
  const int*   ei      =(const int*)  d_in[2];
  const float* Ws1=(const float*)d_in[3];
  const float* as1_src=(const float*)d_in[4];
  const float* as1_dst=(const float*)d_in[5];
  const float* bs1=(const float*)d_in[6];
  const float* Ws2=(const float*)d_in[7];
  const float* as2_src=(const float*)d_in[8];
  const float* as2_dst=(const float*)d_in[9];
  const float* bs2=(const float*)d_in[10];
  const float* wd_emb=(const float*)d_in[11];
  const float* sl_emb=(const float*)d_in[12];
  const float* Wc1=(const float*)d_in[13];
  const float* bc1=(const float*)d_in[14];
  const float* Wc2=(const float*)d_in[15];
  const float* bc2=(const float*)d_in[16];
  const float* Wp1=(const float*)d_in[17];
  const float* bp1=(const float*)d_in[18];
  const float* Wp2=(const float*)d_in[19];
  const float* bp2=(const float*)d_in[20];
  const float* Wt1=(const float*)d_in[21];
  const float* at1_src=(const float*)d_in[22];
  const float* at1_dst=(const float*)d_in[23];
  const float* bt1=(const float*)d_in[24];
  const float* Wt2=(const float*)d_in[25];
  const float* at2_src=(const float*)d_in[26];
  const float* at2_dst=(const float*)d_in[27];
  const float* bt2=(const float*)d_in[28];
  const float* Wh1=(const float*)d_in[29];
  const float* bh1=(const float*)d_in[30];
  const float* Wh2=(const float*)d_in[31];
  const float* bh2=(const float*)d_in[32];

  float* Hout=(float*)d_out;
  float* pred=Hout + (size_t)TT*NN*64;

  char* wsp=(char*)d_ws; size_t off=0;
  auto A=[&](size_t n)->void*{ void* p=wsp+off; off=(off+n+255)&~(size_t)255; return p; };
  u16* rp    =(u16*)A(408*2);
  u32* col2  =(u32*)A((NE+4)*4);
  u16* ordv  =(u16*)A(NN*2);
  f16* Bf1   =(f16*)A(16384*2);
  f16* Bf2   =(f16*)A(4096*2);
  f16* Bfh   =(f16*)A(2048*2);
  f16* Bs1   =(f16*)A(4096*2);
  f16* Bs2   =(f16*)A(1024*2);
  float* wpe_s =(float*)A(128*4);
  float* wpe_d =(float*)A(128*4);
  float* wt1_as=(float*)A(128*4);
  float* wt1_ad=(float*)A(128*4);
  float* w2s   =(float*)A(64*4);
  float* w2d   =(float*)A(64*4);
  float* b_pe2 =(float*)A(256*4);
  float* WcW   =(float*)A(8192*4);
  float* wbal_s=(float*)A(128*4);
  float* wbal_d=(float*)A(128*4);
  float* balc_s=(float*)A(4*4);
  float* balc_d=(float*)A(4*4);
  u32*   xsb   =(u32*)A(6400*4);
  float* Aal_s =(float*)A(1600*4);
  float* Aal_d =(float*)A(1600*4);

  hipLaunchKernelGGL(k_setup, dim3(2), dim3(1024), 0, stream,
                     ei, Wp2,bp2,Wt1,at1_src,at1_dst,Wt2,at2_src,at2_dst,Wh1,Wc2,bc2,Ws1,Ws2,
                     rp,col2,ordv,Bf1,Bf2,Bfh,Bs1,Bs2,
                     wpe_s,wpe_d,wt1_as,wt1_ad,w2s,w2d,b_pe2,WcW,wbal_s,wbal_d,balc_s,balc_d);
  hipLaunchKernelGGL(k_static, dim3(1), dim3(1024), 0, stream,
                     x_static,as1_src,as1_dst,bs1,as2_src,as2_dst,bs2,
                     wt1_as,wt1_ad,Bs1,Bs2,rp,col2,ordv,xsb,Aal_s,Aal_d);
  hipLaunchKernelGGL(k_temporal, dim3(TT), dim3(1024), 0, stream,
                     pf,Wp1,bp1,xsb,Aal_s,Aal_d,wpe_s,wpe_d,Bf1,Bf2,Bfh,
                     WcW,b_pe2,wbal_s,wbal_d,balc_s,balc_d,
                     Wc1,bc1,wd_emb,sl_emb,bt1,w2s,w2d,bt2,bh1,Wh2,bh2,
                     rp,col2,ordv,Hout,pred);
}

// Round 10
// 376.103 us; speedup vs baseline: 1.2935x; 1.0774x over previous
//
#include <hip/hip_runtime.h>

typedef unsigned short u16;
typedef unsigned int   u32;
typedef _Float16 f16;
typedef __attribute__((ext_vector_type(8))) _Float16 f16x8;
typedef __attribute__((ext_vector_type(4))) float f32x4;

#define NN  400
#define EIN 3200
#define NE  3600
#define TT  2016
#define L2E 1.4426950408889634f

__device__ __forceinline__ u32 pk16(float a, float b){
  auto h = __builtin_amdgcn_cvt_pkrtz(a,b);
  union { decltype(h) v; u32 u; } cv; cv.v = h; return cv.u;
}
__device__ __forceinline__ float hlo(u32 w){
  union { u32 u; __fp16 h[2]; } v; v.u=w; return (float)v.h[0];
}
__device__ __forceinline__ float hhi(u32 w){
  union { u32 u; __fp16 h[2]; } v; v.u=w; return (float)v.h[1];
}
// f32 += f16(lo/hi of u32) * f32, single VALU op
__device__ __forceinline__ void fmix_lo(float& a, u32 s, float p){
  asm("v_fma_mix_f32 %0, %1, %2, %0 op_sel:[0,0,0] op_sel_hi:[1,0,0]" : "+v"(a) : "v"(s), "v"(p));
}
__device__ __forceinline__ void fmix_hi(float& a, u32 s, float p){
  asm("v_fma_mix_f32 %0, %1, %2, %0 op_sel:[1,0,0] op_sel_hi:[1,0,0]" : "+v"(a) : "v"(s), "v"(p));
}
// packed f16 pair FMA: a(lo,hi) += h(lo,hi) * p(lo,hi), single VALU op
__device__ __forceinline__ void pkfma(u32& a, u32 h, u32 p){
  asm("v_pk_fma_f16 %0, %1, %2, %0" : "+v"(a) : "v"(h), "v"(p));
}

// =============== setup: block0 = CSR (parallel scatter+sort), block1 = folds + B-frag packs ===============
__global__ __launch_bounds__(1024) void k_setup(
    const int* __restrict__ ei,
    const float* __restrict__ Wp2, const float* __restrict__ bp2,
    const float* __restrict__ Wt1,
    const float* __restrict__ at1_src, const float* __restrict__ at1_dst,
    const float* __restrict__ Wt2, const float* __restrict__ at2_src, const float* __restrict__ at2_dst,
    const float* __restrict__ Wh1,
    const float* __restrict__ Wc2, const float* __restrict__ bc2,
    const float* __restrict__ Ws1, const float* __restrict__ Ws2,
    u16* __restrict__ rp, u32* __restrict__ col2, u16* __restrict__ ord,
    f16* __restrict__ Bf1, f16* __restrict__ Bf2, f16* __restrict__ Bfh,
    f16* __restrict__ Bs1, f16* __restrict__ Bs2,
    float* __restrict__ wpe_s, float* __restrict__ wpe_d,
    float* __restrict__ wt1_as, float* __restrict__ wt1_ad,
    float* __restrict__ w2s, float* __restrict__ w2d,
    float* __restrict__ b_pe2, float* __restrict__ WcW,
    float* __restrict__ wbal_s, float* __restrict__ wbal_d,
    float* __restrict__ balc_s, float* __restrict__ balc_d)
{
  const int tid=threadIdx.x;
  __shared__ int s_src[NE]; __shared__ int s_dst[NE]; __shared__ int s_tmp[NE];
  __shared__ int s_deg[NN]; __shared__ int s_rp[NN+1]; __shared__ int s_cur[NN];
  __shared__ float sWpe[8192];
  __shared__ float sWcW[8192];
  __shared__ float sbpe2[256];
  if(blockIdx.x==0){
    for(int e2=tid;e2<NE;e2+=1024){
      s_src[e2]=(e2<EIN)?ei[e2]:(e2-EIN);
      s_dst[e2]=(e2<EIN)?ei[EIN+e2]:(e2-EIN);
    }
    if(tid<NN) s_deg[tid]=0;
    __syncthreads();
    for(int e2=tid;e2<NE;e2+=1024) atomicAdd(&s_deg[s_dst[e2]],1);
    __syncthreads();
    if(tid<=NN){
      int acc=0;
      for(int j=0;j<tid;j++) acc+=s_deg[j];
      s_rp[tid]=acc;
      rp[tid]=(u16)acc;
      if(tid<NN) s_cur[tid]=acc;
    }
    if(tid==0){
      rp[NN+1]=(u16)NE; rp[NN+2]=(u16)NE; rp[NN+3]=(u16)NE;
      col2[NE]=0; col2[NE+1]=0; col2[NE+2]=0; col2[NE+3]=0;
    }
    __syncthreads();
    for(int e2=tid;e2<NE;e2+=1024){
      int slot=atomicAdd(&s_cur[s_dst[e2]],1);
      s_tmp[slot]=e2;
    }
    __syncthreads();
    if(tid<NN){
      int b=s_rp[tid], en=s_rp[tid+1];
      for(int i=b+1;i<en;i++){
        int key=s_tmp[i]; int j=i-1;
        while(j>=b && s_tmp[j]>key){ s_tmp[j+1]=s_tmp[j]; j--; }
        s_tmp[j+1]=key;
      }
      for(int i=b;i<en;i++){
        u32 s=(u32)s_src[s_tmp[i]];
        col2[i]=((s*144u)<<16)|(s*4u);
      }
      int dg=en-b, rk=0;
      for(int j=0;j<NN;j++){
        int dj=s_rp[j+1]-s_rp[j];
        rk += (dj>dg)||((dj==dg)&&(j<tid));
      }
      ord[rk]=(u16)tid;
    }
  } else {
    for(int i=tid;i<8192;i+=1024){
      int k=i>>8, j=i&255;
      float a=0.f,b=0.f;
      for(int m=0;m<32;m++){
        a+=Wp2[k*32+m]*Wt1[(64+m)*256+j];
        b+=Wc2[k*32+m]*Wt1[(32+m)*256+j];
      }
      sWpe[i]=a; sWcW[i]=b; WcW[i]=b;
    }
    if(tid<256){
      float a=0.f,b=0.f;
      for(int m=0;m<32;m++){ a+=bp2[m]*Wt1[(64+m)*256+tid]; b+=bc2[m]*Wt1[(32+m)*256+tid]; }
      sbpe2[tid]=a+b; b_pe2[tid]=a+b;
    }
    __syncthreads();
    if(tid<128){
      int k=tid>>2,h=tid&3;
      float s=0,d=0,s2=0,d2=0,bs=0,bd=0;
      for(int c=0;c<64;c++){
        float as=at1_src[h*64+c], ad=at1_dst[h*64+c];
        float wv=sWpe[k*256+h*64+c];  s+=wv*as;  d+=wv*ad;
        float w2=Wt1[k*256+h*64+c];   s2+=w2*as; d2+=w2*ad;
        float wc=sWcW[k*256+h*64+c];  bs+=wc*as; bd+=wc*ad;
      }
      wpe_s[tid]=s*L2E; wpe_d[tid]=d*L2E; wt1_as[tid]=s2*L2E; wt1_ad[tid]=d2*L2E;
      wbal_s[tid]=bs*L2E; wbal_d[tid]=bd*L2E;
    }
    if(tid>=128&&tid<192){
      int k=tid-128; float s=0,d=0;
      for(int c=0;c<64;c++){ float wv=Wt2[k*64+c]; s+=wv*at2_src[c]; d+=wv*at2_dst[c]; }
      w2s[k]=s*L2E; w2d[k]=d*L2E;
    }
    if(tid>=192&&tid<196){
      int h=tid-192; float s=0,d=0;
      for(int c=0;c<64;c++){ float v=sbpe2[h*64+c]; s+=v*at1_src[h*64+c]; d+=v*at1_dst[h*64+c]; }
      balc_s[h]=s*L2E; balc_d[h]=d*L2E;
    }
    for(int i=tid;i<16384;i+=1024){
      int j=i&7, ll=(i>>3)&63, ks=(i>>9)&1, nt=(i>>10)&3, h=(i>>12)&3;
      int k=ks*32+(ll>>4)*8+j, c=h*64+nt*16+(ll&15);
      float v=(k<32)? sWpe[k*256+c] : Wt1[(k-32)*256+c];
      Bf1[i]=(f16)v;
    }
    for(int i=tid;i<4096;i+=1024){
      int j=i&7, ll=(i>>3)&63, ks=(i>>9)&1, nt=(i>>10)&3;
      Bf2[i]=(f16)Wt2[(ks*32+(ll>>4)*8+j)*64 + nt*16+(ll&15)];
    }
    for(int i=tid;i<2048;i+=1024){
      int j=i&7, ll=(i>>3)&63, ks=(i>>9)&1, nt=(i>>10)&1;
      Bfh[i]=(f16)Wh1[(ks*32+(ll>>4)*8+j)*32 + nt*16+(ll&15)];
    }
    for(int i=tid;i<4096;i+=1024){
      int j=i&7, ll=(i>>3)&63, nt=(i>>9)&7;
      int k=(ll>>4)*8+j, c=nt*16+(ll&15);
      Bs1[i]=(f16)((k<16)? Ws1[k*128+c] : 0.f);
    }
    for(int i=tid;i<1024;i+=1024){
      int j=i&7, ll=(i>>3)&63, nt=(i>>9)&1;
      int k=(ll>>4)*8+j, c=nt*16+(ll&15);
      Bs2[i]=(f16)Ws2[k*32+c];
    }
  }
}

// =============== static 2-layer GAT (unchanged) ===============
#define KS_X    0
#define KS_H    32000
#define KS_ALS  140800
#define KS_ALD  147200
#define KS_COL  153600
#define KS_RP   160800
#define KS_ORD  161608
#define KS_AS   162408
#define KS_AD   162920
#define KS_END  163432

__global__ __launch_bounds__(1024) void k_static(
    const float* __restrict__ x_static,
    const float* __restrict__ as1_src, const float* __restrict__ as1_dst, const float* __restrict__ bs1,
    const float* __restrict__ as2_src, const float* __restrict__ as2_dst, const float* __restrict__ bs2,
    const float* __restrict__ wt1_as, const float* __restrict__ wt1_ad,
    const f16* __restrict__ Bs1, const f16* __restrict__ Bs2,
    const u16* __restrict__ g_rp, const u32* __restrict__ g_col2, const u16* __restrict__ g_ord,
    u32* __restrict__ xsb, float* __restrict__ Aal_s, float* __restrict__ Aal_d)
{
  __shared__ __align__(16) char smem[KS_END];
  const int tid=threadIdx.x;
  const int l=tid&63, w=tid>>6;
  const int col16=l&15, cr=(l>>4)*4, kbyte=(l>>4)*16;
  const int lane8=tid&7, grp8=tid>>3;
  const int l16=tid&15, g16=tid>>4, hh=l16>>2, cg=l16&3;
  float* ALS=(float*)(smem+KS_ALS);
  float* ALD=(float*)(smem+KS_ALD);
  const u16* COL=(const u16*)(smem+KS_COL);
  const u16* RP =(const u16*)(smem+KS_RP);
  const u16* ORD=(const u16*)(smem+KS_ORD);
  float* AS=(float*)(smem+KS_AS);
  float* AD=(float*)(smem+KS_AD);

  for(int i=tid;i<NN*32;i+=1024){
    int n=i>>5, c=i&31;
    *(f16*)(smem+KS_X+n*80+c*2) = (c<16)? (f16)x_static[n*16+c] : (f16)0.f;
  }
  for(int i=tid;i<NE;i+=1024) ((u16*)(smem+KS_COL))[i]=(u16)((g_col2[i]&0xffffu)>>2);
  if(tid<202) ((u32*)(smem+KS_RP))[tid]=((const u32*)g_rp)[tid];
  else if(tid>=256&&tid<456) ((u32*)(smem+KS_ORD))[tid-256]=((const u32*)g_ord)[tid-256];
  else if(tid>=512&&tid<640){ AS[tid-512]=as1_src[tid-512]*L2E; AD[tid-512]=as1_dst[tid-512]*L2E; }
  __syncthreads();

  {
    f16x8 B[8];
    #pragma unroll
    for(int nt=0;nt<8;nt++) B[nt]=*(const f16x8*)(Bs1+nt*512+l*8);
    for(int mt=w;mt<25;mt+=16){
      f16x8 a=*(const f16x8*)(smem+KS_X+(mt*16+col16)*80+kbyte);
      #pragma unroll
      for(int nt=0;nt<8;nt++){
        f32x4 c={0.f,0.f,0.f,0.f};
        c=__builtin_amdgcn_mfma_f32_16x16x32_f16(a,B[nt],c,0,0,0);
        #pragma unroll
        for(int r=0;r<4;r++)
          *(f16*)(smem+KS_H+(mt*16+cr+r)*272+(nt*16+col16)*2)=(f16)c[r];
      }
    }
  }
  __syncthreads();

  if(tid<NN){
    #pragma unroll
    for(int h=0;h<4;h++){
      const u32* hr=(const u32*)(smem+KS_H+tid*272+h*64);
      float sa=0.f,da=0.f;
      #pragma unroll
      for(int q=0;q<16;q++){
        u32 v=hr[q]; float v0=hlo(v),v1=hhi(v);
        sa=fmaf(v0,AS[h*32+2*q],sa); sa=fmaf(v1,AS[h*32+2*q+1],sa);
        da=fmaf(v0,AD[h*32+2*q],da); da=fmaf(v1,AD[h*32+2*q+1],da);
      }
      ALS[tid*4+h]=sa; ALD[tid*4+h]=da;
    }
  }
  __syncthreads();

  for(int m=0;m<7;m++){
    int di=g16+m*64;
    if(di<NN){
      int d=ORD[di];
      int b=RP[d], en=RP[d+1];
      float ad=ALD[d*4+hh];
      float den=0.f;
      float rt[8]={0.f,0.f,0.f,0.f,0.f,0.f,0.f,0.f};
      for(int j=b;j<en;j++){
        int s=COL[j];
        float v=ALS[s*4+hh]+ad;
        v=fmaxf(v,0.2f*v);
        float p=__builtin_amdgcn_exp2f(v); den+=p;
        uint4 hw=*(const uint4*)(smem+KS_H+s*272+l16*16);
        rt[0]=fmaf(hlo(hw.x),p,rt[0]); rt[1]=fmaf(hhi(hw.x),p,rt[1]);
        rt[2]=fmaf(hlo(hw.y),p,rt[2]); rt[3]=fmaf(hhi(hw.y),p,rt[3]);
        rt[4]=fmaf(hlo(hw.z),p,rt[4]); rt[5]=fmaf(hhi(hw.z),p,rt[5]);
        rt[6]=fmaf(hlo(hw.w),p,rt[6]); rt[7]=fmaf(hhi(hw.w),p,rt[7]);
      }
      float inv=__builtin_amdgcn_rcpf(den);
      float vs[8];
      #pragma unroll
      for(int q=0;q<8;q++){
        float x=rt[q]*inv;
        x+=__shfl_xor(x,4); x+=__shfl_xor(x,8);
        vs[q]=x;
      }
      if(l16<4){
        u32 pk[4];
        #pragma unroll
        for(int q=0;q<4;q++){
          float v0=fmaxf(fmaf(0.25f,vs[2*q],  bs1[cg*8+2*q]),  0.f);
          float v1=fmaxf(fmaf(0.25f,vs[2*q+1],bs1[cg*8+2*q+1]),0.f);
          pk[q]=pk16(v0,v1);
        }
        *(uint4*)(smem+KS_X+d*80+cg*16)=make_uint4(pk[0],pk[1],pk[2],pk[3]);
      }
    }
  }
  __syncthreads();

  {
    f16x8 B[2];
    #pragma unroll
    for(int nt=0;nt<2;nt++) B[nt]=*(const f16x8*)(Bs2+nt*512+l*8);
    for(int mt=w;mt<25;mt+=16){
      f16x8 a=*(const f16x8*)(smem+KS_X+(mt*16+col16)*80+kbyte);
      #pragma unroll
      for(int nt=0;nt<2;nt++){
        f32x4 c={0.f,0.f,0.f,0.f};
        c=__builtin_amdgcn_mfma_f32_16x16x32_f16(a,B[nt],c,0,0,0);
        #pragma unroll
        for(int r=0;r<4;r++)
          *(f16*)(smem+KS_H+(mt*16+cr+r)*80+(nt*16+col16)*2)=(f16)c[r];
      }
    }
  }
  if(tid>=512&&tid<640){ AS[tid-512]=wt1_as[tid-512]; AD[tid-512]=wt1_ad[tid-512]; }
  __syncthreads();

  if(tid<NN){
    const u32* hr=(const u32*)(smem+KS_H+tid*80);
    float sa=0.f,da=0.f;
    #pragma unroll
    for(int q=0;q<16;q++){
      u32 v=hr[q]; float v0=hlo(v),v1=hhi(v);
      sa=fmaf(v0,as2_src[2*q],sa); sa=fmaf(v1,as2_src[2*q+1],sa);
      da=fmaf(v0,as2_dst[2*q],da); da=fmaf(v1,as2_dst[2*q+1],da);
    }
    ALS[tid]=sa*L2E; ALD[tid]=da*L2E;
  }
  __syncthreads();

  #pragma unroll
  for(int m=0;m<4;m++){
    int di=grp8+m*128;
    if(di<NN){
      int d=ORD[di];
      int b=RP[d], en=RP[d+1];
      float ad=ALD[d];
      float den=0.f;
      float rt[4]={0.f,0.f,0.f,0.f};
      for(int j=b;j<en;j++){
        int s=COL[j];
        float v=ALS[s]+ad;
        v=fmaxf(v,0.2f*v);
        float p=__builtin_amdgcn_exp2f(v); den+=p;
        uint2 hw=*(const uint2*)(smem+KS_H+s*80+lane8*8);
        rt[0]=fmaf(hlo(hw.x),p,rt[0]); rt[1]=fmaf(hhi(hw.x),p,rt[1]);
        rt[2]=fmaf(hlo(hw.y),p,rt[2]); rt[3]=fmaf(hhi(hw.y),p,rt[3]);
      }
      float inv=__builtin_amdgcn_rcpf(den);
      float xq[4];
      #pragma unroll
      for(int q=0;q<4;q++) xq[q]=fmaxf(fmaf(rt[q],inv,bs2[lane8*4+q]),0.f);
      float ps[4]={0.f,0.f,0.f,0.f}, pd[4]={0.f,0.f,0.f,0.f};
      #pragma unroll
      for(int q=0;q<4;q++){
        int k=lane8*4+q;
        #pragma unroll
        for(int h2=0;h2<4;h2++){ ps[h2]=fmaf(xq[q],AS[k*4+h2],ps[h2]); pd[h2]=fmaf(xq[q],AD[k*4+h2],pd[h2]); }
      }
      #pragma unroll
      for(int h2=0;h2<4;h2++){
        ps[h2]+=__shfl_xor(ps[h2],1); ps[h2]+=__shfl_xor(ps[h2],2); ps[h2]+=__shfl_xor(ps[h2],4);
        pd[h2]+=__shfl_xor(pd[h2],1); pd[h2]+=__shfl_xor(pd[h2],2); pd[h2]+=__shfl_xor(pd[h2],4);
      }
      if(lane8==0){
        #pragma unroll
        for(int h2=0;h2<4;h2++){ Aal_s[d*4+h2]=ps[h2]; Aal_d[d*4+h2]=pd[h2]; }
      }
      xsb[d*16+lane8*2+0]=pk16(xq[0],xq[1]);
      xsb[d*16+lane8*2+1]=pk16(xq[2],xq[3]);
    }
  }
}

// =============== fused temporal: pk_fma_f16 gather + swapped-operand MFMA ===============
#define OT_A    0
#define OT_H    57600
#define OT_ALS  115200
#define OT_ALD  121600
#define OT_COL  128000
#define OT_RP   142416
#define OT_ORD  143232
#define OT_BP   144032
#define OT_WPES 145056
#define OT_WPED 145568
#define OT_W2S  146080
#define OT_W2D  146336
#define OT_BT2  146592
#define OT_BH1  146848
#define OT_WH2  146976
#define OT_BPMT 147104
#define OT_C1   147360
#define OT_FEAT 147488
#define OT_BAL  147616
#define OT_END  147648

__global__ __launch_bounds__(1024) void k_temporal(
    const float* __restrict__ pf, const float* __restrict__ Wp1, const float* __restrict__ bp1,
    const u32* __restrict__ xsb, const float* __restrict__ Aal_s, const float* __restrict__ Aal_d,
    const float* __restrict__ wpe_sg, const float* __restrict__ wpe_dg,
    const f16* __restrict__ Bf1, const f16* __restrict__ Bf2, const f16* __restrict__ Bfh,
    const float* __restrict__ WcW, const float* __restrict__ b_pe2,
    const float* __restrict__ wbal_s, const float* __restrict__ wbal_d,
    const float* __restrict__ balc_s, const float* __restrict__ balc_d,
    const float* __restrict__ Wc1, const float* __restrict__ bc1,
    const float* __restrict__ wd_emb, const float* __restrict__ sl_emb,
    const float* __restrict__ bt1, const float* __restrict__ w2sg, const float* __restrict__ w2dg,
    const float* __restrict__ bt2g, const float* __restrict__ bh1g,
    const float* __restrict__ Wh2g, const float* __restrict__ bh2,
    const u16* __restrict__ g_rp, const u32* __restrict__ g_col2, const u16* __restrict__ g_ord,
    float* __restrict__ Hout, float* __restrict__ pred)
{
  __shared__ __align__(16) char smem[OT_END];
  const int bid=blockIdx.x;
  const int t=(bid&7)*252+(bid>>3);   // XCD-chunked bijective swizzle
  const int tid=threadIdx.x;
  const int l=tid&63, w=tid>>6;
  const int lane4=tid&3, grp4=tid>>2;
  const int col16=l&15, cr=(l>>4)*4, kbyte=(l>>4)*16;

  float4 pA=make_float4(0,0,0,0), pB=make_float4(0,0,0,0);
  if(tid<NN){ const float4* pp=(const float4*)(pf+((size_t)tid*TT+(size_t)t)*8); pA=pp[0]; pB=pp[1]; }

  // ---- phase 0: staging ----
  for(int i=tid;i<3604;i+=1024) ((u32*)(smem+OT_COL))[i]=g_col2[i];
  for(int i=tid;i<6400;i+=1024){ int n=i>>4,q=i&15; *(u32*)(smem+OT_A+n*144+64+q*4)=xsb[i]; }
  if(tid<202) ((u32*)(smem+OT_RP))[tid]=((const u32*)g_rp)[tid];
  else if(tid>=256&&tid<456) ((u32*)(smem+OT_ORD))[tid-256]=((const u32*)g_ord)[tid-256];
  else if(tid>=512&&tid<640){ ((float*)(smem+OT_WPES))[tid-512]=wpe_sg[tid-512]; ((float*)(smem+OT_WPED))[tid-512]=wpe_dg[tid-512]; }
  else if(tid>=640&&tid<704){ ((float*)(smem+OT_W2S))[tid-640]=w2sg[tid-640]; ((float*)(smem+OT_W2D))[tid-640]=w2dg[tid-640]; }
  else if(tid>=704&&tid<768){ ((float*)(smem+OT_BT2))[tid-704]=bt2g[tid-704]; }
  else if(tid>=768&&tid<800){ ((float*)(smem+OT_BH1))[tid-768]=bh1g[tid-768]; ((float*)(smem+OT_WH2))[tid-768]=Wh2g[tid-768]; }
  else if(tid>=832&&tid<864){
    int q=tid-832;
    const int wd=t/288, sl=t%288;
    float v=0.f;
    if(q<8) v=wd_emb[wd*8+q];
    else if(q<24) v=sl_emb[sl*16+(q-8)];
    else if(q==24||q==25){ float ta=0.021816615649929116f*(float)sl; v=(q==24)?__sinf(ta):__cosf(ta); }
    else if(q==26||q==27){ float wa=0.8975979010256552f*(float)wd; v=(q==26)?__sinf(wa):__cosf(wa); }
    else if(q==28) v=(wd>=5)?1.f:0.f;
    ((float*)(smem+OT_FEAT))[q]=v;
  }
  __syncthreads();

  // ---- phase 1: c1 (calendar) || P1 + logits ----
  if(tid>=512&&tid<544){
    int q=tid-512;
    float a=bc1[q];
    const float* F=(const float*)(smem+OT_FEAT);
    for(int k=0;k<29;k++) a+=F[k]*Wc1[k*32+q];
    ((float*)(smem+OT_C1))[q]=fmaxf(a,0.f);
  }
  if(tid<NN){
    float px[8]={pA.x,pA.y,pA.z,pA.w,pB.x,pB.y,pB.z,pB.w};
    float pv[32];
    #pragma unroll
    for(int k2=0;k2<32;k2+=2){
      float a0=bp1[k2], a1=bp1[k2+1];
      #pragma unroll
      for(int i2=0;i2<8;i2++){ a0=fmaf(px[i2],Wp1[i2*32+k2],a0); a1=fmaf(px[i2],Wp1[i2*32+k2+1],a1); }
      a0=fmaxf(a0,0.f); a1=fmaxf(a1,0.f);
      pv[k2]=a0; pv[k2+1]=a1;
      *(u32*)(smem+OT_A+tid*144+k2*2)=pk16(a0,a1);
    }
    const float* WS=(const float*)(smem+OT_WPES);
    const float* WD=(const float*)(smem+OT_WPED);
    #pragma unroll
    for(int h=0;h<4;h++){
      float sa=Aal_s[tid*4+h], da=Aal_d[tid*4+h];
      #pragma unroll
      for(int k2=0;k2<32;k2++){ sa=fmaf(pv[k2],WS[k2*4+h],sa); da=fmaf(pv[k2],WD[k2*4+h],da); }
      ((float*)(smem+OT_ALS))[tid*4+h]=sa;
      ((float*)(smem+OT_ALD))[tid*4+h]=da;
    }
  }
  __syncthreads();

  // MFMA with weights as A-operand (D row = feature, D col = node) -> packed b64 stores, immediate.
  auto mfma_L1=[&](int h){
    f16x8 Bw0[4],Bw1[4];
    #pragma unroll
    for(int nt=0;nt<4;nt++){
      Bw0[nt]=*(const f16x8*)(Bf1+(((h*4+nt)*2+0)*512+l*8));
      Bw1[nt]=*(const f16x8*)(Bf1+(((h*4+nt)*2+1)*512+l*8));
    }
    for(int mt=w;mt<25;mt+=16){
      const char* arow=smem+OT_A+(mt*16+col16)*144;
      f16x8 a0=*(const f16x8*)(arow+kbyte);
      f16x8 a1=*(const f16x8*)(arow+64+kbyte);
      int n=mt*16+col16;
      #pragma unroll
      for(int nt=0;nt<4;nt++){
        f32x4 c={0.f,0.f,0.f,0.f};
        c=__builtin_amdgcn_mfma_f32_16x16x32_f16(Bw0[nt],a0,c,0,0,0);
        c=__builtin_amdgcn_mfma_f32_16x16x32_f16(Bw1[nt],a1,c,0,0,0);
        *(uint2*)(smem+OT_H+n*144+(nt*16+cr)*2)=make_uint2(pk16(c[0],c[1]),pk16(c[2],c[3]));
      }
    }
  };

  // ---- phase 2: MFMA head0 || bpre || Bal ----
  mfma_L1(0);
  if(tid<256){
    float a=b_pe2[tid];
    const float* C1=(const float*)(smem+OT_C1);
    for(int k2=0;k2<32;k2++) a=fmaf(C1[k2],WcW[k2*256+tid],a);
    ((float*)(smem+OT_BP))[tid]=a;
  }
  if(tid>=256&&tid<264){
    int h=tid&3; bool isd=(tid>=260);
    const float* C1=(const float*)(smem+OT_C1);
    const float* wb=isd?wbal_d:wbal_s;
    float a=isd?balc_d[h]:balc_s[h];
    for(int k2=0;k2<32;k2++) a=fmaf(C1[k2],wb[k2*4+h],a);
    ((float*)(smem+OT_BAL))[(isd?4:0)+h]=a;
  }
  __syncthreads();

  const u16* RP  =(const u16*)(smem+OT_RP);
  const u16* ORD =(const u16*)(smem+OT_ORD);
  const u32* COL2=(const u32*)(smem+OT_COL);
  const char* HB = smem+OT_H+lane4*32;

  float acc[2][16];
  #pragma unroll
  for(int m=0;m<2;m++){
    #pragma unroll
    for(int q=0;q<16;q++) acc[m][q]=0.f;
  }

  // ---- L1: 4 heads, 4-lane-group pk_fma gather (snake order) ----
  for(int h=0;h<4;h++){
    if(h==0&&tid<64){
      const float* BP=(const float*)(smem+OT_BP);
      ((float*)(smem+OT_BPMT))[tid]=0.25f*(BP[tid]+BP[64+tid]+BP[128+tid]+BP[192+tid])+bt1[tid];
    }
    const float* ALD=(const float*)(smem+OT_ALD);
    const char* ALSb=smem+OT_ALS+h*4;
    float bsd=((const float*)(smem+OT_BAL))[h]+((const float*)(smem+OT_BAL))[4+h];
    #pragma unroll
    for(int m=0;m<2;m++){
      int di = m ? (511-grp4) : grp4;
      u32 rt2[8]={0,0,0,0,0,0,0,0};
      float inv=0.f;
      if(di<NN){
        int d=ORD[di];
        int b=RP[d], en=RP[d+1];
        float ad=ALD[d*4+h]+bsd;
        float den=0.f;
        for(int j=b;j<en;j++){
          u32 cv=COL2[j];
          float alv=*(const float*)(ALSb+((cv&0xffffu)<<2));
          float v=alv+ad;
          v=fmaxf(v,0.2f*v);
          float p=__builtin_amdgcn_exp2f(v); den+=p;
          u32 pp=pk16(p,p);
          const char* hp=HB+(cv>>16);
          uint4 h0=*(const uint4*)(hp);
          uint4 h1=*(const uint4*)(hp+16);
          pkfma(rt2[0],h0.x,pp); pkfma(rt2[1],h0.y,pp);
          pkfma(rt2[2],h0.z,pp); pkfma(rt2[3],h0.w,pp);
          pkfma(rt2[4],h1.x,pp); pkfma(rt2[5],h1.y,pp);
          pkfma(rt2[6],h1.z,pp); pkfma(rt2[7],h1.w,pp);
        }
        inv=__builtin_amdgcn_rcpf(den);
      }
      #pragma unroll
      for(int q=0;q<8;q++){
        acc[m][2*q]  =fmaf(hlo(rt2[q]),inv,acc[m][2*q]);
        acc[m][2*q+1]=fmaf(hhi(rt2[q]),inv,acc[m][2*q+1]);
      }
    }
    __syncthreads();
    if(h<3){ mfma_L1(h+1); __syncthreads(); }
  }

  // ---- g1 = relu(0.25*acc + bpmt) + logits2 + pack ----
  {
    const float* BPMT=(const float*)(smem+OT_BPMT);
    const float* W2S=(const float*)(smem+OT_W2S);
    const float* W2D=(const float*)(smem+OT_W2D);
    #pragma unroll
    for(int m=0;m<2;m++){
      int di = m ? (511-grp4) : grp4;
      if(di<NN){
        int d=ORD[di];
        float g[16];
        #pragma unroll
        for(int q=0;q<16;q++) g[q]=fmaxf(fmaf(0.25f,acc[m][q],BPMT[lane4*16+q]),0.f);
        float ss=0.f,dd2=0.f;
        #pragma unroll
        for(int q=0;q<16;q++){ ss=fmaf(g[q],W2S[lane4*16+q],ss); dd2=fmaf(g[q],W2D[lane4*16+q],dd2); }
        ss+=__shfl_xor(ss,1); ss+=__shfl_xor(ss,2);
        dd2+=__shfl_xor(dd2,1); dd2+=__shfl_xor(dd2,2);
        if(lane4==0){ ((float*)(smem+OT_ALS))[d]=ss; ((float*)(smem+OT_ALD))[d]=dd2; }
        uint4 pk0,pk1;
        pk0.x=pk16(g[0],g[1]);   pk0.y=pk16(g[2],g[3]);   pk0.z=pk16(g[4],g[5]);   pk0.w=pk16(g[6],g[7]);
        pk1.x=pk16(g[8],g[9]);   pk1.y=pk16(g[10],g[11]); pk1.z=pk16(g[12],g[13]); pk1.w=pk16(g[14],g[15]);
        *(uint4*)(smem+OT_A+d*144+lane4*32)=pk0;
        *(uint4*)(smem+OT_A+d*144+lane4*32+16)=pk1;
      }
    }
  }
  __syncthreads();

  // ---- L2 MFMA (swapped operands, packed stores) ----
  {
    f16x8 Bw0[4],Bw1[4];
    #pragma unroll
    for(int nt=0;nt<4;nt++){
      Bw0[nt]=*(const f16x8*)(Bf2+((nt*2+0)*512+l*8));
      Bw1[nt]=*(const f16x8*)(Bf2+((nt*2+1)*512+l*8));
    }
    for(int mt=w;mt<25;mt+=16){
      const char* arow=smem+OT_A+(mt*16+col16)*144;
      f16x8 a0=*(const f16x8*)(arow+kbyte);
      f16x8 a1=*(const f16x8*)(arow+64+kbyte);
      int n=mt*16+col16;
      #pragma unroll
      for(int nt=0;nt<4;nt++){
        f32x4 c={0.f,0.f,0.f,0.f};
        c=__builtin_amdgcn_mfma_f32_16x16x32_f16(Bw0[nt],a0,c,0,0,0);
        c=__builtin_amdgcn_mfma_f32_16x16x32_f16(Bw1[nt],a1,c,0,0,0);
        *(uint2*)(smem+OT_H+n*144+(nt*16+cr)*2)=make_uint2(pk16(c[0],c[1]),pk16(c[2],c[3]));
      }
    }
  }
  __syncthreads();

  // ---- L2 agg (pk_fma) -> Hout + pack for MLP ----
  {
    const float* ALD=(const float*)(smem+OT_ALD);
    const float* BT2=(const float*)(smem+OT_BT2);
    #pragma unroll
    for(int m=0;m<2;m++){
      int di = m ? (511-grp4) : grp4;
      if(di<NN){
        int d=ORD[di];
        int b=RP[d], en=RP[d+1];
        float ad=ALD[d];
        float den=0.f;
        u32 rt2[8]={0,0,0,0,0,0,0,0};
        for(int j=b;j<en;j++){
          u32 cv=COL2[j];
          float alv=*(const float*)(smem+OT_ALS+(cv&0xffffu));
          float v=alv+ad;
          v=fmaxf(v,0.2f*v);
          float p=__builtin_amdgcn_exp2f(v); den+=p;
          u32 pp=pk16(p,p);
          const char* hp=HB+(cv>>16);
          uint4 h0=*(const uint4*)(hp);
          uint4 h1=*(const uint4*)(hp+16);
          pkfma(rt2[0],h0.x,pp); pkfma(rt2[1],h0.y,pp);
          pkfma(rt2[2],h0.z,pp); pkfma(rt2[3],h0.w,pp);
          pkfma(rt2[4],h1.x,pp); pkfma(rt2[5],h1.y,pp);
          pkfma(rt2[6],h1.z,pp); pkfma(rt2[7],h1.w,pp);
        }
        float inv=__builtin_amdgcn_rcpf(den);
        float hv[16];
        #pragma unroll
        for(int q=0;q<8;q++){
          hv[2*q]  =fmaxf(fmaf(hlo(rt2[q]),inv,BT2[lane4*16+2*q]),  0.f);
          hv[2*q+1]=fmaxf(fmaf(hhi(rt2[q]),inv,BT2[lane4*16+2*q+1]),0.f);
        }
        float* hp2=Hout+((size_t)t*NN+d)*64+lane4*16;
        *(float4*)(hp2)   =make_float4(hv[0],hv[1],hv[2],hv[3]);
        *(float4*)(hp2+4) =make_float4(hv[4],hv[5],hv[6],hv[7]);
        *(float4*)(hp2+8) =make_float4(hv[8],hv[9],hv[10],hv[11]);
        *(float4*)(hp2+12)=make_float4(hv[12],hv[13],hv[14],hv[15]);
        uint4 pk0,pk1;
        pk0.x=pk16(hv[0],hv[1]);   pk0.y=pk16(hv[2],hv[3]);   pk0.z=pk16(hv[4],hv[5]);   pk0.w=pk16(hv[6],hv[7]);
        pk1.x=pk16(hv[8],hv[9]);   pk1.y=pk16(hv[10],hv[11]); pk1.z=pk16(hv[12],hv[13]); pk1.w=pk16(hv[14],hv[15]);
        *(uint4*)(smem+OT_A+d*144+lane4*32)=pk0;
        *(uint4*)(smem+OT_A+d*144+lane4*32+16)=pk1;
      }
    }
  }
  __syncthreads();

  // ---- head MLP (swapped operands, f32x4 stores): pj = relu(H@Wh1+bh1) ----
  {
    f16x8 Bw0[2],Bw1[2];
    #pragma unroll
    for(int nt=0;nt<2;nt++){
      Bw0[nt]=*(const f16x8*)(Bfh+((nt*2+0)*512+l*8));
      Bw1[nt]=*(const f16x8*)(Bfh+((nt*2+1)*512+l*8));
    }
    for(int mt=w;mt<25;mt+=16){
      const char* arow=smem+OT_A+(mt*16+col16)*144;
      f16x8 a0=*(const f16x8*)(arow+kbyte);
      f16x8 a1=*(const f16x8*)(arow+64+kbyte);
      int n=mt*16+col16;
      #pragma unroll
      for(int nt=0;nt<2;nt++){
        float4 bj=*(const float4*)(smem+OT_BH1+(nt*16+cr)*4);
        f32x4 c={bj.x,bj.y,bj.z,bj.w};
        c=__builtin_amdgcn_mfma_f32_16x16x32_f16(Bw0[nt],a0,c,0,0,0);
        c=__builtin_amdgcn_mfma_f32_16x16x32_f16(Bw1[nt],a1,c,0,0,0);
        f32x4 co={fmaxf(c[0],0.f),fmaxf(c[1],0.f),fmaxf(c[2],0.f),fmaxf(c[3],0.f)};
        *(f32x4*)(smem+OT_H+n*144+(nt*16+cr)*4)=co;
      }
    }
  }
  __syncthreads();

  // ---- pred ----
  {
    const float* WH2=(const float*)(smem+OT_WH2);
    float wv[8];
    #pragma unroll
    for(int q=0;q<8;q++) wv[q]=WH2[lane4*8+q];
    float bb=bh2[0];
    #pragma unroll
    for(int m=0;m<2;m++){
      int di = m ? (511-grp4) : grp4;
      if(di<NN){
        int d=ORD[di];
        float4 p0=*(const float4*)(smem+OT_H+d*144+lane4*32);
        float4 p1=*(const float4*)(smem+OT_H+d*144+lane4*32+16);
        float sp=p0.x*wv[0]+p0.y*wv[1]+p0.z*wv[2]+p0.w*wv[3]
                +p1.x*wv[4]+p1.y*wv[5]+p1.z*wv[6]+p1.w*wv[7];
        sp+=__shfl_xor(sp,1); sp+=__shfl_xor(sp,2);
        if(lane4==0) pred[(size_t)t*NN+d]=sp+bb;
      }
    }
  }
}

extern "C" void kernel_launch(void* const* d_in, const int* in_sizes, int n_in,
                              void* d_out, int out_size, void* d_ws, size_t ws_size,
                              hipStream_t stream) {
  const float* x_static=(const float*)d_in[0];
  const float* pf      =(const float*)d_in[1];
  const int*   ei      =(const int*)  d_in[2];
  const float* Ws1=(const float*)d_in[3];
  const float* as1_src=(const float*)d_in[4];
  const float* as1_dst=(const float*)d_in[5];
  const float* bs1=(const float*)d_in[6];
  const float* Ws2=(const float*)d_in[7];
  const float* as2_src=(const float*)d_in[8];
  const float* as2_dst=(const float*)d_in[9];
  const float* bs2=(const float*)d_in[10];
  const float* wd_emb=(const float*)d_in[11];
  const float* sl_emb=(const float*)d_in[12];
  const float* Wc1=(const float*)d_in[13];
  const float* bc1=(const float*)d_in[14];
  const float* Wc2=(const float*)d_in[15];
  const float* bc2=(const float*)d_in[16];
  const float* Wp1=(const float*)d_in[17];
  const float* bp1=(const float*)d_in[18];
  const float* Wp2=(const float*)d_in[19];
  const float* bp2=(const float*)d_in[20];
  const float* Wt1=(const float*)d_in[21];
  const float* at1_src=(const float*)d_in[22];
  const float* at1_dst=(const float*)d_in[23];
  const float* bt1=(const float*)d_in[24];
  const float* Wt2=(const float*)d_in[25];
  const float* at2_src=(const float*)d_in[26];
  const float* at2_dst=(const float*)d_in[27];
  const float* bt2=(const float*)d_in[28];
  const float* Wh1=(const float*)d_in[29];
  const float* bh1=(const float*)d_in[30];
  const float* Wh2=(const float*)d_in[31];
  const float* bh2=(const float*)d_in[32];

  float* Hout=(float*)d_out;
  float* pred=Hout + (size_t)TT*NN*64;

  char* wsp=(char*)d_ws; size_t off=0;
  auto A=[&](size_t n)->void*{ void* p=wsp+off; off=(off+n+255)&~(size_t)255; return p; };
  u16* rp    =(u16*)A(408*2);
  u32* col2  =(u32*)A((NE+4)*4);
  u16* ordv  =(u16*)A(NN*2);
  f16* Bf1   =(f16*)A(16384*2);
  f16* Bf2   =(f16*)A(4096*2);
  f16* Bfh   =(f16*)A(2048*2);
  f16* Bs1   =(f16*)A(4096*2);
  f16* Bs2   =(f16*)A(1024*2);
  float* wpe_s =(float*)A(128*4);
  float* wpe_d =(float*)A(128*4);
  float* wt1_as=(float*)A(128*4);
  float* wt1_ad=(float*)A(128*4);
  float* w2s   =(float*)A(64*4);
  float* w2d   =(float*)A(64*4);
  float* b_pe2 =(float*)A(256*4);
  float* WcW   =(float*)A(8192*4);
  float* wbal_s=(float*)A(128*4);
  float* wbal_d=(float*)A(128*4);
  float* balc_s=(float*)A(4*4);
  float* balc_d=(float*)A(4*4);
  u32*   xsb   =(u32*)A(6400*4);
  float* Aal_s =(float*)A(1600*4);
  float* Aal_d =(float*)A(1600*4);

  hipLaunchKernelGGL(k_setup, dim3(2), dim3(1024), 0, stream,
                     ei, Wp2,bp2,Wt1,at1_src,at1_dst,Wt2,at2_src,at2_dst,Wh1,Wc2,bc2,Ws1,Ws2,
                     rp,col2,ordv,Bf1,Bf2,Bfh,Bs1,Bs2,
                     wpe_s,wpe_d,wt1_as,wt1_ad,w2s,w2d,b_pe2,WcW,wbal_s,wbal_d,balc_s,balc_d);
  hipLaunchKernelGGL(k_static, dim3(1), dim3(1024), 0, stream,
                     x_static,as1_src,as1_dst,bs1,as2_src,as2_dst,bs2,
                     wt1_as,wt1_ad,Bs1,Bs2,rp,col2,ordv,xsb,Aal_s,Aal_d);
  hipLaunchKernelGGL(k_temporal, dim3(TT), dim3(1024), 0, stream,
                     pf,Wp1,bp1,xsb,Aal_s,Aal_d,wpe_s,wpe_d,Bf1,Bf2,Bfh,
                     WcW,b_pe2,wbal_s,wbal_d,balc_s,balc_d,
                     Wc1,bc1,wd_emb,sl_emb,bt1,w2s,w2d,bt2,bh1,Wh2,bh2,
                     rp,col2,ordv,Hout,pred);
}